// Round 1
// baseline (290.780 us; speedup 1.0000x reference)
//
#include <hip/hip_runtime.h>
#include <math.h>

#define NUM_NODES 2048
#define BATCH 2
#define NHEAD 8
#define SEQ 168
#define HID 256
#define DHEAD 32
#define UPART 80
#define UTOP 40
#define L0C 81
#define L1C 39
#define L2C 19
#define C0 8
#define C1 16
#define C2 32
#define FCIN 608   // 32*19
#define ROWS 4096  // BATCH*NUM_NODES

// ---------------- Kernel 1: conv chain (conv+relu+LN x3) ----------------
__global__ __launch_bounds__(128) void conv_chain_kernel(
    const float* __restrict__ x,
    const float* __restrict__ w0, const float* __restrict__ b0,
    const float* __restrict__ w1, const float* __restrict__ b1,
    const float* __restrict__ w2, const float* __restrict__ b2,
    const float* __restrict__ g0, const float* __restrict__ be0,
    const float* __restrict__ g1, const float* __restrict__ be1,
    const float* __restrict__ g2, const float* __restrict__ be2,
    float* __restrict__ Hout)
{
    __shared__ float xs[SEQ];
    __shared__ float h0[C0][L0C];
    __shared__ float h1[C1][L1C];
    __shared__ float h2[C2][L2C];
    __shared__ float w0s[C0*7];
    __shared__ float w1s[C1*C0*5];
    __shared__ float w2s[C2*C1*3];

    const int row = blockIdx.x;
    const int tid = threadIdx.x;

    for (int i = tid; i < SEQ; i += 128) xs[i] = x[row*SEQ + i];
    for (int i = tid; i < C0*7; i += 128) w0s[i] = w0[i];
    for (int i = tid; i < C1*C0*5; i += 128) w1s[i] = w1[i];
    for (int i = tid; i < C2*C1*3; i += 128) w2s[i] = w2[i];
    __syncthreads();

    // conv0 (1->8, k=7, s=2) + relu
    for (int idx = tid; idx < C0*L0C; idx += 128) {
        int c = idx / L0C, t = idx % L0C;
        float acc = b0[c];
        #pragma unroll
        for (int j = 0; j < 7; ++j) acc += w0s[c*7+j] * xs[2*t+j];
        h0[c][t] = fmaxf(acc, 0.f);
    }
    __syncthreads();
    // LN over 81 per channel: 16 threads/channel
    {
        int c = tid >> 4, lane = tid & 15;
        float s = 0.f, s2 = 0.f;
        for (int t = lane; t < L0C; t += 16) { float v = h0[c][t]; s += v; s2 += v*v; }
        #pragma unroll
        for (int m = 8; m >= 1; m >>= 1) { s += __shfl_xor(s, m); s2 += __shfl_xor(s2, m); }
        float mean = s / (float)L0C;
        float inv = rsqrtf(s2 / (float)L0C - mean*mean + 1e-5f);
        for (int t = lane; t < L0C; t += 16)
            h0[c][t] = (h0[c][t] - mean) * inv * g0[t] + be0[t];
    }
    __syncthreads();
    // conv1 (8->16, k=5, s=2) + relu
    for (int idx = tid; idx < C1*L1C; idx += 128) {
        int c = idx / L1C, t = idx % L1C;
        float acc = b1[c];
        for (int ci = 0; ci < C0; ++ci) {
            #pragma unroll
            for (int j = 0; j < 5; ++j) acc += w1s[(c*C0+ci)*5+j] * h0[ci][2*t+j];
        }
        h1[c][t] = fmaxf(acc, 0.f);
    }
    __syncthreads();
    // LN over 39 per channel: 8 threads/channel
    {
        int c = tid >> 3, lane = tid & 7;
        float s = 0.f, s2 = 0.f;
        for (int t = lane; t < L1C; t += 8) { float v = h1[c][t]; s += v; s2 += v*v; }
        #pragma unroll
        for (int m = 4; m >= 1; m >>= 1) { s += __shfl_xor(s, m); s2 += __shfl_xor(s2, m); }
        float mean = s / (float)L1C;
        float inv = rsqrtf(s2 / (float)L1C - mean*mean + 1e-5f);
        for (int t = lane; t < L1C; t += 8)
            h1[c][t] = (h1[c][t] - mean) * inv * g1[t] + be1[t];
    }
    __syncthreads();
    // conv2 (16->32, k=3, s=2) + relu
    for (int idx = tid; idx < C2*L2C; idx += 128) {
        int c = idx / L2C, t = idx % L2C;
        float acc = b2[c];
        for (int ci = 0; ci < C1; ++ci) {
            #pragma unroll
            for (int j = 0; j < 3; ++j) acc += w2s[(c*C1+ci)*3+j] * h1[ci][2*t+j];
        }
        h2[c][t] = fmaxf(acc, 0.f);
    }
    __syncthreads();
    // LN over 19 per channel: 4 threads/channel
    {
        int c = tid >> 2, lane = tid & 3;
        float s = 0.f, s2 = 0.f;
        for (int t = lane; t < L2C; t += 4) { float v = h2[c][t]; s += v; s2 += v*v; }
        #pragma unroll
        for (int m = 2; m >= 1; m >>= 1) { s += __shfl_xor(s, m); s2 += __shfl_xor(s2, m); }
        float mean = s / (float)L2C;
        float inv = rsqrtf(s2 / (float)L2C - mean*mean + 1e-5f);
        for (int t = lane; t < L2C; t += 4)
            h2[c][t] = (h2[c][t] - mean) * inv * g2[t] + be2[t];
    }
    __syncthreads();
    for (int i = tid; i < FCIN; i += 128)
        Hout[(size_t)row*FCIN + i] = h2[i / L2C][i % L2C];
}

// ---------------- Kernel 2: fc+relu+LN3, then q,k projections ----------------
__global__ __launch_bounds__(256) void fc_qk_kernel(
    const float* __restrict__ Hin,
    const float* __restrict__ fc_w, const float* __restrict__ fc_b,
    const float* __restrict__ g3, const float* __restrict__ be3,
    const float* __restrict__ q_w, const float* __restrict__ q_b,
    const float* __restrict__ k_w, const float* __restrict__ k_b,
    float* __restrict__ q_out, float* __restrict__ k_out)
{
    __shared__ float Hs[16][FCIN];
    __shared__ float hm[16][HID];
    const int row0 = blockIdx.x * 16;
    const int tid = threadIdx.x;

    for (int i = tid; i < 16*FCIN; i += 256)
        Hs[i / FCIN][i % FCIN] = Hin[(size_t)row0*FCIN + i];
    __syncthreads();

    float acc[16];
    // fc: 608 -> 256, thread owns output column `tid`
    {
        float bias = fc_b[tid];
        #pragma unroll
        for (int r = 0; r < 16; ++r) acc[r] = bias;
        const float4* wrow = (const float4*)(fc_w + (size_t)tid*FCIN);
        for (int kk = 0; kk < FCIN/4; ++kk) {
            float4 w4 = wrow[kk];
            #pragma unroll
            for (int r = 0; r < 16; ++r) {
                float4 h4 = *(const float4*)&Hs[r][kk*4];
                acc[r] += w4.x*h4.x + w4.y*h4.y + w4.z*h4.z + w4.w*h4.w;
            }
        }
        #pragma unroll
        for (int r = 0; r < 16; ++r) hm[r][tid] = fmaxf(acc[r], 0.f);
    }
    __syncthreads();
    // LN3 over 256 per row; one wave handles 4 rows
    {
        int wave = tid >> 6, lane = tid & 63;
        for (int r = wave; r < 16; r += 4) {
            float s = 0.f, s2 = 0.f;
            #pragma unroll
            for (int i = 0; i < 4; ++i) { float v = hm[r][lane + 64*i]; s += v; s2 += v*v; }
            #pragma unroll
            for (int m = 32; m >= 1; m >>= 1) { s += __shfl_xor(s, m); s2 += __shfl_xor(s2, m); }
            float mean = s / (float)HID;
            float inv = rsqrtf(s2 / (float)HID - mean*mean + 1e-5f);
            #pragma unroll
            for (int i = 0; i < 4; ++i) {
                int o = lane + 64*i;
                hm[r][o] = (hm[r][o] - mean) * inv * g3[o] + be3[o];
            }
        }
    }
    __syncthreads();
    // q projection
    {
        float bias = q_b[tid];
        #pragma unroll
        for (int r = 0; r < 16; ++r) acc[r] = bias;
        const float4* wrow = (const float4*)(q_w + (size_t)tid*HID);
        for (int j = 0; j < HID/4; ++j) {
            float4 w4 = wrow[j];
            #pragma unroll
            for (int r = 0; r < 16; ++r) {
                float4 h4 = *(const float4*)&hm[r][j*4];
                acc[r] += w4.x*h4.x + w4.y*h4.y + w4.z*h4.z + w4.w*h4.w;
            }
        }
        #pragma unroll
        for (int r = 0; r < 16; ++r) q_out[(size_t)(row0+r)*HID + tid] = acc[r];
    }
    // k projection
    {
        float bias = k_b[tid];
        #pragma unroll
        for (int r = 0; r < 16; ++r) acc[r] = bias;
        const float4* wrow = (const float4*)(k_w + (size_t)tid*HID);
        for (int j = 0; j < HID/4; ++j) {
            float4 w4 = wrow[j];
            #pragma unroll
            for (int r = 0; r < 16; ++r) {
                float4 h4 = *(const float4*)&hm[r][j*4];
                acc[r] += w4.x*h4.x + w4.y*h4.y + w4.z*h4.z + w4.w*h4.w;
            }
        }
        #pragma unroll
        for (int r = 0; r < 16; ++r) k_out[(size_t)(row0+r)*HID + tid] = acc[r];
    }
}

// ---------------- Kernel 3: QK_sample + M ----------------
__global__ __launch_bounds__(256) void qk_sample_kernel(
    const float* __restrict__ q, const float* __restrict__ k,
    const int* __restrict__ idx_g, float* __restrict__ M)
{
    __shared__ int sidx[UPART];
    __shared__ float qrow[HID];
    __shared__ float qk[NHEAD][UPART];
    const int bl = blockIdx.x;            // b*2048 + l
    const int b = bl >> 11, l = bl & (NUM_NODES-1);
    const int tid = threadIdx.x;
    if (tid < UPART) sidx[tid] = idx_g[l*UPART + tid];
    qrow[tid] = q[(size_t)bl*HID + tid];
    __syncthreads();
    for (int task = tid; task < NHEAD*UPART; task += 256) {
        int h = task / UPART, s = task % UPART;
        const float4* kp = (const float4*)(k + (size_t)(b*NUM_NODES + sidx[s])*HID + h*DHEAD);
        const float4* qp = (const float4*)(qrow + h*DHEAD);
        float acc = 0.f;
        #pragma unroll
        for (int d4 = 0; d4 < 8; ++d4) {
            float4 kv = kp[d4], qv = qp[d4];
            acc += qv.x*kv.x + qv.y*kv.y + qv.z*kv.z + qv.w*kv.w;
        }
        qk[h][s] = acc;
    }
    __syncthreads();
    if (tid < NHEAD) {
        float mx = -INFINITY, sm = 0.f;
        for (int s = 0; s < UPART; ++s) { float v = qk[tid][s]; mx = fmaxf(mx, v); sm += v; }
        M[(size_t)(b*NHEAD + tid)*NUM_NODES + l] = mx - sm / (float)NUM_NODES;
    }
}

// ---------------- fill inv with -1 ----------------
__global__ void fill_inv_kernel(int* __restrict__ inv)
{
    inv[blockIdx.x*256 + threadIdx.x] = -1;
}

// ---------------- Kernel 4: top-40 per (b,h), tie-break = smaller index ----------------
__global__ __launch_bounds__(256) void topk_kernel(
    const float* __restrict__ M, int* __restrict__ Mtop, int* __restrict__ inv)
{
    __shared__ float Ms[NUM_NODES];
    __shared__ float rv[4];
    __shared__ int ri[4];
    const int bh = blockIdx.x;  // b*8+h
    const int b = bh >> 3, h = bh & 7;
    const int tid = threadIdx.x;
    for (int i = tid; i < NUM_NODES; i += 256) Ms[i] = M[(size_t)bh*NUM_NODES + i];
    __syncthreads();
    for (int u = 0; u < UTOP; ++u) {
        float bv = -INFINITY; int bi = NUM_NODES;
        for (int i = tid; i < NUM_NODES; i += 256) {
            float v = Ms[i];
            if (v > bv || (v == bv && i < bi)) { bv = v; bi = i; }
        }
        #pragma unroll
        for (int m = 32; m >= 1; m >>= 1) {
            float ov = __shfl_xor(bv, m); int oi = __shfl_xor(bi, m);
            if (ov > bv || (ov == bv && oi < bi)) { bv = ov; bi = oi; }
        }
        if ((tid & 63) == 0) { rv[tid >> 6] = bv; ri[tid >> 6] = bi; }
        __syncthreads();
        if (tid == 0) {
            float fv = rv[0]; int fi = ri[0];
            #pragma unroll
            for (int w = 1; w < 4; ++w) {
                if (rv[w] > fv || (rv[w] == fv && ri[w] < fi)) { fv = rv[w]; fi = ri[w]; }
            }
            Mtop[bh*UTOP + u] = fi;
            inv[(size_t)(b*NUM_NODES + fi)*NHEAD + h] = u;
            Ms[fi] = -INFINITY;
        }
        __syncthreads();
    }
}

// ---------------- Kernel 5: scores + softmax + threshold ----------------
__global__ __launch_bounds__(256) void attn_kernel(
    const float* __restrict__ q, const float* __restrict__ k,
    const int* __restrict__ Mtop, float* __restrict__ attn)
{
    __shared__ float qsel[DHEAD];
    __shared__ float sc[NUM_NODES];
    __shared__ float red[8];
    const int blk = blockIdx.x;   // (b*8+h)*40+u
    const int bh = blk / UTOP, u = blk % UTOP;
    const int b = bh >> 3, h = bh & 7;
    const int tid = threadIdx.x;
    const int lsel = Mtop[bh*UTOP + u];
    if (tid < DHEAD) qsel[tid] = q[(size_t)(b*NUM_NODES + lsel)*HID + h*DHEAD + tid];
    __syncthreads();
    const float scale = 0.17677669529663687f; // 1/sqrt(32)
    float lmax = -INFINITY;
    for (int j = tid; j < NUM_NODES; j += 256) {
        const float4* kp = (const float4*)(k + (size_t)(b*NUM_NODES + j)*HID + h*DHEAD);
        const float4* qp = (const float4*)qsel;
        float acc = 0.f;
        #pragma unroll
        for (int d4 = 0; d4 < 8; ++d4) {
            float4 kv = kp[d4], qv = qp[d4];
            acc += qv.x*kv.x + qv.y*kv.y + qv.z*kv.z + qv.w*kv.w;
        }
        acc *= scale;
        sc[j] = acc;
        lmax = fmaxf(lmax, acc);
    }
    #pragma unroll
    for (int m = 32; m >= 1; m >>= 1) lmax = fmaxf(lmax, __shfl_xor(lmax, m));
    if ((tid & 63) == 0) red[tid >> 6] = lmax;
    __syncthreads();
    const float gmax = fmaxf(fmaxf(red[0], red[1]), fmaxf(red[2], red[3]));
    float lsum = 0.f;
    for (int j = tid; j < NUM_NODES; j += 256) {
        float e = expf(sc[j] - gmax);
        sc[j] = e;
        lsum += e;
    }
    #pragma unroll
    for (int m = 32; m >= 1; m >>= 1) lsum += __shfl_xor(lsum, m);
    if ((tid & 63) == 0) red[4 + (tid >> 6)] = lsum;
    __syncthreads();
    const float rinv = 1.0f / (red[4] + red[5] + red[6] + red[7]);
    const float thr = 1.0f / (float)NUM_NODES;
    for (int j = tid; j < NUM_NODES; j += 256) {
        float v = sc[j] * rinv;
        if (v < thr) v = 0.f;
        attn[(size_t)blk*NUM_NODES + j] = v;
    }
}

// ---------------- Kernel 6: combine heads -> output ----------------
__global__ __launch_bounds__(256) void combine_kernel(
    const float* __restrict__ attn, const int* __restrict__ inv,
    float* __restrict__ out)
{
    __shared__ int us[NHEAD];
    const int bl = blockIdx.x;  // b*2048+l
    const int b = bl >> 11;
    const int tid = threadIdx.x;
    if (tid < NHEAD) us[tid] = inv[(size_t)bl*NHEAD + tid];
    __syncthreads();
    const size_t outbase = (size_t)bl * NUM_NODES;
    for (int j = tid; j < NUM_NODES; j += 256) {
        float s = 0.f;
        #pragma unroll
        for (int h = 0; h < NHEAD; ++h) {
            int u = us[h];
            if (u >= 0) s += attn[(size_t)((b*NHEAD + h)*UTOP + u)*NUM_NODES + j];
        }
        out[outbase + j] = s * 0.125f;
    }
}

extern "C" void kernel_launch(void* const* d_in, const int* in_sizes, int n_in,
                              void* d_out, int out_size, void* d_ws, size_t ws_size,
                              hipStream_t stream) {
    const float* x      = (const float*)d_in[0];
    const float* w0     = (const float*)d_in[1];
    const float* b0     = (const float*)d_in[2];
    const float* w1     = (const float*)d_in[3];
    const float* b1     = (const float*)d_in[4];
    const float* w2     = (const float*)d_in[5];
    const float* b2     = (const float*)d_in[6];
    const float* g0     = (const float*)d_in[7];
    const float* be0    = (const float*)d_in[8];
    const float* g1     = (const float*)d_in[9];
    const float* be1    = (const float*)d_in[10];
    const float* g2     = (const float*)d_in[11];
    const float* be2    = (const float*)d_in[12];
    const float* g3     = (const float*)d_in[13];
    const float* be3    = (const float*)d_in[14];
    const float* fc_w   = (const float*)d_in[15];
    const float* fc_b   = (const float*)d_in[16];
    const float* q_w    = (const float*)d_in[17];
    const float* q_b    = (const float*)d_in[18];
    const float* k_w    = (const float*)d_in[19];
    const float* k_b    = (const float*)d_in[20];
    const int* idx_g    = (const int*)d_in[21];
    float* out = (float*)d_out;

    float* Hflat   = (float*)d_ws;                       // 4096*608
    float* q_ws    = Hflat + (size_t)ROWS*FCIN;          // 4096*256
    float* k_ws    = q_ws + (size_t)ROWS*HID;            // 4096*256
    float* M_ws    = k_ws + (size_t)ROWS*HID;            // 2*8*2048
    float* attn_ws = M_ws + (size_t)BATCH*NHEAD*NUM_NODES;   // 2*8*40*2048
    int*   Mtop    = (int*)(attn_ws + (size_t)BATCH*NHEAD*UTOP*NUM_NODES); // 640
    int*   inv     = Mtop + BATCH*NHEAD*UTOP;            // 2*2048*8

    fill_inv_kernel<<<(BATCH*NUM_NODES*NHEAD)/256, 256, 0, stream>>>(inv);
    conv_chain_kernel<<<ROWS, 128, 0, stream>>>(x, w0, b0, w1, b1, w2, b2,
                                                g0, be0, g1, be1, g2, be2, Hflat);
    fc_qk_kernel<<<ROWS/16, 256, 0, stream>>>(Hflat, fc_w, fc_b, g3, be3,
                                              q_w, q_b, k_w, k_b, q_ws, k_ws);
    qk_sample_kernel<<<BATCH*NUM_NODES, 256, 0, stream>>>(q_ws, k_ws, idx_g, M_ws);
    topk_kernel<<<BATCH*NHEAD, 256, 0, stream>>>(M_ws, Mtop, inv);
    attn_kernel<<<BATCH*NHEAD*UTOP, 256, 0, stream>>>(q_ws, k_ws, Mtop, attn_ws);
    combine_kernel<<<BATCH*NUM_NODES, 256, 0, stream>>>(attn_ws, inv, out);
}

// Round 3
// 282.795 us; speedup vs baseline: 1.0282x; 1.0282x over previous
//
#include <hip/hip_runtime.h>
#include <math.h>

#define NUM_NODES 2048
#define BATCH 2
#define NHEAD 8
#define SEQ 168
#define HID 256
#define DHEAD 32
#define UPART 80
#define UTOP 40
#define L0C 81
#define L1C 39
#define L2C 19
#define C0 8
#define C1 16
#define C2 32
#define FCIN 608   // 32*19
#define ROWS 4096  // BATCH*NUM_NODES

// ---------------- Kernel 0: transpose the three weight matrices ----------------
// fc_w (256x608) -> fc_wT (608x256); q_w,k_w (256x256) -> T
__global__ __launch_bounds__(256) void transpose3_kernel(
    const float* __restrict__ fc_w, const float* __restrict__ q_w, const float* __restrict__ k_w,
    float* __restrict__ fc_wT, float* __restrict__ q_wT, float* __restrict__ k_wT)
{
    __shared__ float t[32][33];
    const int z = blockIdx.z;
    const float* in = (z == 0) ? fc_w : ((z == 1) ? q_w : k_w);
    float* out      = (z == 0) ? fc_wT : ((z == 1) ? q_wT : k_wT);
    const int M = 256;                    // rows of in
    const int N = (z == 0) ? FCIN : HID;  // cols of in
    const int bx = blockIdx.x * 32;       // col tile of in
    const int by = blockIdx.y * 32;       // row tile of in
    if (bx >= N) return;
    const int tx = threadIdx.x & 31, ty0 = threadIdx.x >> 5;
    for (int i = ty0; i < 32; i += 8) {
        int r = by + i, c = bx + tx;
        if (r < M && c < N) t[i][tx] = in[(size_t)r * N + c];
    }
    __syncthreads();
    for (int i = ty0; i < 32; i += 8) {
        int r = bx + i, c = by + tx;      // out is N x M
        if (r < N && c < M) out[(size_t)r * M + c] = t[tx][i];
    }
}

// ---------------- Kernel 1: conv chain (conv+relu+LN x3) ----------------
__global__ __launch_bounds__(128) void conv_chain_kernel(
    const float* __restrict__ x,
    const float* __restrict__ w0, const float* __restrict__ b0,
    const float* __restrict__ w1, const float* __restrict__ b1,
    const float* __restrict__ w2, const float* __restrict__ b2,
    const float* __restrict__ g0, const float* __restrict__ be0,
    const float* __restrict__ g1, const float* __restrict__ be1,
    const float* __restrict__ g2, const float* __restrict__ be2,
    float* __restrict__ Hout)
{
    __shared__ float xs[SEQ];
    __shared__ float h0[C0][L0C];
    __shared__ float h1[C1][L1C];
    __shared__ float h2[C2][L2C];
    __shared__ float w0s[C0*7];
    __shared__ float w1s[C1*C0*5];
    __shared__ float w2s[C2*C1*3];

    const int row = blockIdx.x;
    const int tid = threadIdx.x;

    for (int i = tid; i < SEQ; i += 128) xs[i] = x[row*SEQ + i];
    for (int i = tid; i < C0*7; i += 128) w0s[i] = w0[i];
    for (int i = tid; i < C1*C0*5; i += 128) w1s[i] = w1[i];
    for (int i = tid; i < C2*C1*3; i += 128) w2s[i] = w2[i];
    __syncthreads();

    // conv0 (1->8, k=7, s=2) + relu
    for (int idx = tid; idx < C0*L0C; idx += 128) {
        int c = idx / L0C, t = idx % L0C;
        float acc = b0[c];
        #pragma unroll
        for (int j = 0; j < 7; ++j) acc += w0s[c*7+j] * xs[2*t+j];
        h0[c][t] = fmaxf(acc, 0.f);
    }
    __syncthreads();
    {
        int c = tid >> 4, lane = tid & 15;
        float s = 0.f, s2 = 0.f;
        for (int t = lane; t < L0C; t += 16) { float v = h0[c][t]; s += v; s2 += v*v; }
        #pragma unroll
        for (int m = 8; m >= 1; m >>= 1) { s += __shfl_xor(s, m); s2 += __shfl_xor(s2, m); }
        float mean = s / (float)L0C;
        float inv = rsqrtf(s2 / (float)L0C - mean*mean + 1e-5f);
        for (int t = lane; t < L0C; t += 16)
            h0[c][t] = (h0[c][t] - mean) * inv * g0[t] + be0[t];
    }
    __syncthreads();
    // conv1 (8->16, k=5, s=2) + relu
    for (int idx = tid; idx < C1*L1C; idx += 128) {
        int c = idx / L1C, t = idx % L1C;
        float acc = b1[c];
        for (int ci = 0; ci < C0; ++ci) {
            #pragma unroll
            for (int j = 0; j < 5; ++j) acc += w1s[(c*C0+ci)*5+j] * h0[ci][2*t+j];
        }
        h1[c][t] = fmaxf(acc, 0.f);
    }
    __syncthreads();
    {
        int c = tid >> 3, lane = tid & 7;
        float s = 0.f, s2 = 0.f;
        for (int t = lane; t < L1C; t += 8) { float v = h1[c][t]; s += v; s2 += v*v; }
        #pragma unroll
        for (int m = 4; m >= 1; m >>= 1) { s += __shfl_xor(s, m); s2 += __shfl_xor(s2, m); }
        float mean = s / (float)L1C;
        float inv = rsqrtf(s2 / (float)L1C - mean*mean + 1e-5f);
        for (int t = lane; t < L1C; t += 8)
            h1[c][t] = (h1[c][t] - mean) * inv * g1[t] + be1[t];
    }
    __syncthreads();
    // conv2 (16->32, k=3, s=2) + relu
    for (int idx = tid; idx < C2*L2C; idx += 128) {
        int c = idx / L2C, t = idx % L2C;
        float acc = b2[c];
        for (int ci = 0; ci < C1; ++ci) {
            #pragma unroll
            for (int j = 0; j < 3; ++j) acc += w2s[(c*C1+ci)*3+j] * h1[ci][2*t+j];
        }
        h2[c][t] = fmaxf(acc, 0.f);
    }
    __syncthreads();
    {
        int c = tid >> 2, lane = tid & 3;
        float s = 0.f, s2 = 0.f;
        for (int t = lane; t < L2C; t += 4) { float v = h2[c][t]; s += v; s2 += v*v; }
        #pragma unroll
        for (int m = 2; m >= 1; m >>= 1) { s += __shfl_xor(s, m); s2 += __shfl_xor(s2, m); }
        float mean = s / (float)L2C;
        float inv = rsqrtf(s2 / (float)L2C - mean*mean + 1e-5f);
        for (int t = lane; t < L2C; t += 4)
            h2[c][t] = (h2[c][t] - mean) * inv * g2[t] + be2[t];
    }
    __syncthreads();
    for (int i = tid; i < FCIN; i += 128)
        Hout[(size_t)row*FCIN + i] = h2[i / L2C][i % L2C];
}

// ---------------- Kernel 2: fc+relu+LN3 + q,k projections (FMA-bound layout) ----------------
// Block: 16 rows x 256 cols, 256 threads = 4 waves = 2 row-halves x 2 k-halves.
// Weights read transposed (wT[k][col]) so lanes load coalesced float4; H/hm read
// wave-uniform (broadcast). Partials reduced via 16KB LDS.
__global__ __launch_bounds__(256) void fc_qk_kernel(
    const float* __restrict__ Hin,
    const float* __restrict__ fc_wT, const float* __restrict__ fc_b,
    const float* __restrict__ g3, const float* __restrict__ be3,
    const float* __restrict__ q_wT, const float* __restrict__ q_b,
    const float* __restrict__ k_wT, const float* __restrict__ k_b,
    float* __restrict__ q_out, float* __restrict__ k_out)
{
    __shared__ float part[16][HID];   // 16KB: partials from kh==1 waves
    __shared__ float hm[16][HID];     // 16KB: post-LN activations

    const int tid  = threadIdx.x;
    const int lane = tid & 63;
    const int wave = tid >> 6;
    const int rh   = __builtin_amdgcn_readfirstlane(wave >> 1);  // row half 0/1
    const int kh   = __builtin_amdgcn_readfirstlane(wave & 1);   // k half 0/1
    const int c0   = lane * 4;                                   // 4 contiguous cols
    const int r0   = blockIdx.x * 16;
    const int rbase = __builtin_amdgcn_readfirstlane(r0 + rh * 8);

    float4 acc[8];

    // ---------- fc partial over this wave's k-half ----------
    #pragma unroll
    for (int r = 0; r < 8; ++r) acc[r] = make_float4(0.f, 0.f, 0.f, 0.f);
    {
        const int kbeg = kh * (FCIN/2), kend = kbeg + FCIN/2;
        for (int k = kbeg; k < kend; k += 4) {
            float4 w0 = *(const float4*)(fc_wT + (size_t)(k+0)*HID + c0);
            float4 w1 = *(const float4*)(fc_wT + (size_t)(k+1)*HID + c0);
            float4 w2 = *(const float4*)(fc_wT + (size_t)(k+2)*HID + c0);
            float4 w3 = *(const float4*)(fc_wT + (size_t)(k+3)*HID + c0);
            #pragma unroll
            for (int r = 0; r < 8; ++r) {
                float4 h4 = *(const float4*)(Hin + (size_t)(rbase + r)*FCIN + k);
                acc[r].x += h4.x*w0.x + h4.y*w1.x + h4.z*w2.x + h4.w*w3.x;
                acc[r].y += h4.x*w0.y + h4.y*w1.y + h4.z*w2.y + h4.w*w3.y;
                acc[r].z += h4.x*w0.z + h4.y*w1.z + h4.z*w2.z + h4.w*w3.z;
                acc[r].w += h4.x*w0.w + h4.y*w1.w + h4.z*w2.w + h4.w*w3.w;
            }
        }
    }
    if (kh == 1) {
        #pragma unroll
        for (int r = 0; r < 8; ++r) *(float4*)&part[rh*8 + r][c0] = acc[r];
    }
    __syncthreads();   // S1

    // ---------- reduce + bias + relu + LN3 -> hm (kh==0 waves) ----------
    if (kh == 0) {
        float4 b4 = *(const float4*)(fc_b + c0);
        float4 gg = *(const float4*)(g3 + c0);
        float4 bb = *(const float4*)(be3 + c0);
        #pragma unroll
        for (int r = 0; r < 8; ++r) {
            const int row = rh*8 + r;
            float4 p = *(const float4*)&part[row][c0];
            float e0 = fmaxf(acc[r].x + p.x + b4.x, 0.f);
            float e1 = fmaxf(acc[r].y + p.y + b4.y, 0.f);
            float e2 = fmaxf(acc[r].z + p.z + b4.z, 0.f);
            float e3 = fmaxf(acc[r].w + p.w + b4.w, 0.f);
            float s  = e0 + e1 + e2 + e3;
            float s2 = e0*e0 + e1*e1 + e2*e2 + e3*e3;
            #pragma unroll
            for (int m = 32; m >= 1; m >>= 1) { s += __shfl_xor(s, m); s2 += __shfl_xor(s2, m); }
            float mean = s * (1.f/256.f);
            float inv  = rsqrtf(s2 * (1.f/256.f) - mean*mean + 1e-5f);
            float4 o;
            o.x = (e0 - mean) * inv * gg.x + bb.x;
            o.y = (e1 - mean) * inv * gg.y + bb.y;
            o.z = (e2 - mean) * inv * gg.z + bb.z;
            o.w = (e3 - mean) * inv * gg.w + bb.w;
            *(float4*)&hm[row][c0] = o;
        }
    }
    __syncthreads();   // S2

    // ---------- q projection ----------
    #pragma unroll
    for (int r = 0; r < 8; ++r) acc[r] = make_float4(0.f, 0.f, 0.f, 0.f);
    {
        const int kbeg = kh * (HID/2), kend = kbeg + HID/2;
        for (int k = kbeg; k < kend; k += 4) {
            float4 w0 = *(const float4*)(q_wT + (size_t)(k+0)*HID + c0);
            float4 w1 = *(const float4*)(q_wT + (size_t)(k+1)*HID + c0);
            float4 w2 = *(const float4*)(q_wT + (size_t)(k+2)*HID + c0);
            float4 w3 = *(const float4*)(q_wT + (size_t)(k+3)*HID + c0);
            #pragma unroll
            for (int r = 0; r < 8; ++r) {
                float4 h4 = *(const float4*)&hm[rh*8 + r][k];
                acc[r].x += h4.x*w0.x + h4.y*w1.x + h4.z*w2.x + h4.w*w3.x;
                acc[r].y += h4.x*w0.y + h4.y*w1.y + h4.z*w2.y + h4.w*w3.y;
                acc[r].z += h4.x*w0.z + h4.y*w1.z + h4.z*w2.z + h4.w*w3.z;
                acc[r].w += h4.x*w0.w + h4.y*w1.w + h4.z*w2.w + h4.w*w3.w;
            }
        }
    }
    if (kh == 1) {
        #pragma unroll
        for (int r = 0; r < 8; ++r) *(float4*)&part[rh*8 + r][c0] = acc[r];
    }
    __syncthreads();   // S3
    if (kh == 0) {
        float4 b4 = *(const float4*)(q_b + c0);
        #pragma unroll
        for (int r = 0; r < 8; ++r) {
            const int row = rh*8 + r;
            float4 p = *(const float4*)&part[row][c0];
            float4 o;
            o.x = acc[r].x + p.x + b4.x;
            o.y = acc[r].y + p.y + b4.y;
            o.z = acc[r].z + p.z + b4.z;
            o.w = acc[r].w + p.w + b4.w;
            *(float4*)(q_out + (size_t)(r0 + row)*HID + c0) = o;
        }
    }

    // ---------- k projection ----------
    #pragma unroll
    for (int r = 0; r < 8; ++r) acc[r] = make_float4(0.f, 0.f, 0.f, 0.f);
    {
        const int kbeg = kh * (HID/2), kend = kbeg + HID/2;
        for (int k = kbeg; k < kend; k += 4) {
            float4 w0 = *(const float4*)(k_wT + (size_t)(k+0)*HID + c0);
            float4 w1 = *(const float4*)(k_wT + (size_t)(k+1)*HID + c0);
            float4 w2 = *(const float4*)(k_wT + (size_t)(k+2)*HID + c0);
            float4 w3 = *(const float4*)(k_wT + (size_t)(k+3)*HID + c0);
            #pragma unroll
            for (int r = 0; r < 8; ++r) {
                float4 h4 = *(const float4*)&hm[rh*8 + r][k];
                acc[r].x += h4.x*w0.x + h4.y*w1.x + h4.z*w2.x + h4.w*w3.x;
                acc[r].y += h4.x*w0.y + h4.y*w1.y + h4.z*w2.y + h4.w*w3.y;
                acc[r].z += h4.x*w0.z + h4.y*w1.z + h4.z*w2.z + h4.w*w3.z;
                acc[r].w += h4.x*w0.w + h4.y*w1.w + h4.z*w2.w + h4.w*w3.w;
            }
        }
    }
    __syncthreads();   // S4: kh0's q-partial reads are done before part is rewritten
    if (kh == 1) {
        #pragma unroll
        for (int r = 0; r < 8; ++r) *(float4*)&part[rh*8 + r][c0] = acc[r];
    }
    __syncthreads();   // S5
    if (kh == 0) {
        float4 b4 = *(const float4*)(k_b + c0);
        #pragma unroll
        for (int r = 0; r < 8; ++r) {
            const int row = rh*8 + r;
            float4 p = *(const float4*)&part[row][c0];
            float4 o;
            o.x = acc[r].x + p.x + b4.x;
            o.y = acc[r].y + p.y + b4.y;
            o.z = acc[r].z + p.z + b4.z;
            o.w = acc[r].w + p.w + b4.w;
            *(float4*)(k_out + (size_t)(r0 + row)*HID + c0) = o;
        }
    }
}

// ---------------- Kernel 3: QK_sample + M ----------------
__global__ __launch_bounds__(256) void qk_sample_kernel(
    const float* __restrict__ q, const float* __restrict__ k,
    const int* __restrict__ idx_g, float* __restrict__ M)
{
    __shared__ int sidx[UPART];
    __shared__ float qrow[HID];
    __shared__ float qk[NHEAD][UPART];
    const int bl = blockIdx.x;            // b*2048 + l
    const int b = bl >> 11, l = bl & (NUM_NODES-1);
    const int tid = threadIdx.x;
    if (tid < UPART) sidx[tid] = idx_g[l*UPART + tid];
    qrow[tid] = q[(size_t)bl*HID + tid];
    __syncthreads();
    for (int task = tid; task < NHEAD*UPART; task += 256) {
        int h = task / UPART, s = task % UPART;
        const float4* kp = (const float4*)(k + (size_t)(b*NUM_NODES + sidx[s])*HID + h*DHEAD);
        const float4* qp = (const float4*)(qrow + h*DHEAD);
        float acc = 0.f;
        #pragma unroll
        for (int d4 = 0; d4 < 8; ++d4) {
            float4 kv = kp[d4], qv = qp[d4];
            acc += qv.x*kv.x + qv.y*kv.y + qv.z*kv.z + qv.w*kv.w;
        }
        qk[h][s] = acc;
    }
    __syncthreads();
    if (tid < NHEAD) {
        float mx = -INFINITY, sm = 0.f;
        for (int s = 0; s < UPART; ++s) { float v = qk[tid][s]; mx = fmaxf(mx, v); sm += v; }
        M[(size_t)(b*NHEAD + tid)*NUM_NODES + l] = mx - sm / (float)NUM_NODES;
    }
}

// ---------------- fill inv with -1 ----------------
__global__ void fill_inv_kernel(int* __restrict__ inv)
{
    inv[blockIdx.x*256 + threadIdx.x] = -1;
}

// ---------------- Kernel 4: top-40 per (b,h), tie-break = smaller index ----------------
__global__ __launch_bounds__(256) void topk_kernel(
    const float* __restrict__ M, int* __restrict__ Mtop, int* __restrict__ inv)
{
    __shared__ float Ms[NUM_NODES];
    __shared__ float rv[4];
    __shared__ int ri[4];
    const int bh = blockIdx.x;  // b*8+h
    const int b = bh >> 3, h = bh & 7;
    const int tid = threadIdx.x;
    for (int i = tid; i < NUM_NODES; i += 256) Ms[i] = M[(size_t)bh*NUM_NODES + i];
    __syncthreads();
    for (int u = 0; u < UTOP; ++u) {
        float bv = -INFINITY; int bi = NUM_NODES;
        for (int i = tid; i < NUM_NODES; i += 256) {
            float v = Ms[i];
            if (v > bv || (v == bv && i < bi)) { bv = v; bi = i; }
        }
        #pragma unroll
        for (int m = 32; m >= 1; m >>= 1) {
            float ov = __shfl_xor(bv, m); int oi = __shfl_xor(bi, m);
            if (ov > bv || (ov == bv && oi < bi)) { bv = ov; bi = oi; }
        }
        if ((tid & 63) == 0) { rv[tid >> 6] = bv; ri[tid >> 6] = bi; }
        __syncthreads();
        if (tid == 0) {
            float fv = rv[0]; int fi = ri[0];
            #pragma unroll
            for (int w = 1; w < 4; ++w) {
                if (rv[w] > fv || (rv[w] == fv && ri[w] < fi)) { fv = rv[w]; fi = ri[w]; }
            }
            Mtop[bh*UTOP + u] = fi;
            inv[(size_t)(b*NUM_NODES + fi)*NHEAD + h] = u;
            Ms[fi] = -INFINITY;
        }
        __syncthreads();
    }
}

// ---------------- Kernel 5: scores + softmax + threshold ----------------
__global__ __launch_bounds__(256) void attn_kernel(
    const float* __restrict__ q, const float* __restrict__ k,
    const int* __restrict__ Mtop, float* __restrict__ attn)
{
    __shared__ float qsel[DHEAD];
    __shared__ float sc[NUM_NODES];
    __shared__ float red[8];
    const int blk = blockIdx.x;   // (b*8+h)*40+u
    const int bh = blk / UTOP, u = blk % UTOP;
    const int b = bh >> 3, h = bh & 7;
    const int tid = threadIdx.x;
    const int lsel = Mtop[bh*UTOP + u];
    if (tid < DHEAD) qsel[tid] = q[(size_t)(b*NUM_NODES + lsel)*HID + h*DHEAD + tid];
    __syncthreads();
    const float scale = 0.17677669529663687f; // 1/sqrt(32)
    float lmax = -INFINITY;
    for (int j = tid; j < NUM_NODES; j += 256) {
        const float4* kp = (const float4*)(k + (size_t)(b*NUM_NODES + j)*HID + h*DHEAD);
        const float4* qp = (const float4*)qsel;
        float acc = 0.f;
        #pragma unroll
        for (int d4 = 0; d4 < 8; ++d4) {
            float4 kv = kp[d4], qv = qp[d4];
            acc += qv.x*kv.x + qv.y*kv.y + qv.z*kv.z + qv.w*kv.w;
        }
        acc *= scale;
        sc[j] = acc;
        lmax = fmaxf(lmax, acc);
    }
    #pragma unroll
    for (int m = 32; m >= 1; m >>= 1) lmax = fmaxf(lmax, __shfl_xor(lmax, m));
    if ((tid & 63) == 0) red[tid >> 6] = lmax;
    __syncthreads();
    const float gmax = fmaxf(fmaxf(red[0], red[1]), fmaxf(red[2], red[3]));
    float lsum = 0.f;
    for (int j = tid; j < NUM_NODES; j += 256) {
        float e = expf(sc[j] - gmax);
        sc[j] = e;
        lsum += e;
    }
    #pragma unroll
    for (int m = 32; m >= 1; m >>= 1) lsum += __shfl_xor(lsum, m);
    if ((tid & 63) == 0) red[4 + (tid >> 6)] = lsum;
    __syncthreads();
    const float rinv = 1.0f / (red[4] + red[5] + red[6] + red[7]);
    const float thr = 1.0f / (float)NUM_NODES;
    for (int j = tid; j < NUM_NODES; j += 256) {
        float v = sc[j] * rinv;
        if (v < thr) v = 0.f;
        attn[(size_t)blk*NUM_NODES + j] = v;
    }
}

// ---------------- Kernel 6: combine heads -> output ----------------
__global__ __launch_bounds__(256) void combine_kernel(
    const float* __restrict__ attn, const int* __restrict__ inv,
    float* __restrict__ out)
{
    __shared__ int us[NHEAD];
    const int bl = blockIdx.x;  // b*2048+l
    const int b = bl >> 11;
    const int tid = threadIdx.x;
    if (tid < NHEAD) us[tid] = inv[(size_t)bl*NHEAD + tid];
    __syncthreads();
    const size_t outbase = (size_t)bl * NUM_NODES;
    for (int j = tid; j < NUM_NODES; j += 256) {
        float s = 0.f;
        #pragma unroll
        for (int h = 0; h < NHEAD; ++h) {
            int u = us[h];
            if (u >= 0) s += attn[(size_t)((b*NHEAD + h)*UTOP + u)*NUM_NODES + j];
        }
        out[outbase + j] = s * 0.125f;
    }
}

extern "C" void kernel_launch(void* const* d_in, const int* in_sizes, int n_in,
                              void* d_out, int out_size, void* d_ws, size_t ws_size,
                              hipStream_t stream) {
    const float* x      = (const float*)d_in[0];
    const float* w0     = (const float*)d_in[1];
    const float* b0     = (const float*)d_in[2];
    const float* w1     = (const float*)d_in[3];
    const float* b1     = (const float*)d_in[4];
    const float* w2     = (const float*)d_in[5];
    const float* b2     = (const float*)d_in[6];
    const float* g0     = (const float*)d_in[7];
    const float* be0    = (const float*)d_in[8];
    const float* g1     = (const float*)d_in[9];
    const float* be1    = (const float*)d_in[10];
    const float* g2     = (const float*)d_in[11];
    const float* be2    = (const float*)d_in[12];
    const float* g3     = (const float*)d_in[13];
    const float* be3    = (const float*)d_in[14];
    const float* fc_w   = (const float*)d_in[15];
    const float* fc_b   = (const float*)d_in[16];
    const float* q_w    = (const float*)d_in[17];
    const float* q_b    = (const float*)d_in[18];
    const float* k_w    = (const float*)d_in[19];
    const float* k_b    = (const float*)d_in[20];
    const int* idx_g    = (const int*)d_in[21];
    float* out = (float*)d_out;

    float* Hflat   = (float*)d_ws;                       // 4096*608
    float* q_ws    = Hflat + (size_t)ROWS*FCIN;          // 4096*256
    float* k_ws    = q_ws + (size_t)ROWS*HID;            // 4096*256
    float* M_ws    = k_ws + (size_t)ROWS*HID;            // 2*8*2048
    float* attn_ws = M_ws + (size_t)BATCH*NHEAD*NUM_NODES;   // 2*8*40*2048
    int*   Mtop    = (int*)(attn_ws + (size_t)BATCH*NHEAD*UTOP*NUM_NODES); // 640
    int*   inv     = Mtop + BATCH*NHEAD*UTOP;            // 2*2048*8
    float* fc_wT   = (float*)(inv + (size_t)BATCH*NUM_NODES*NHEAD); // 608*256
    float* q_wT    = fc_wT + (size_t)FCIN*HID;           // 256*256
    float* k_wT    = q_wT + (size_t)HID*HID;             // 256*256

    fill_inv_kernel<<<(BATCH*NUM_NODES*NHEAD)/256, 256, 0, stream>>>(inv);
    {
        dim3 tgrid((FCIN + 31)/32, (HID + 31)/32, 3);
        transpose3_kernel<<<tgrid, 256, 0, stream>>>(fc_w, q_w, k_w, fc_wT, q_wT, k_wT);
    }
    conv_chain_kernel<<<ROWS, 128, 0, stream>>>(x, w0, b0, w1, b1, w2, b2,
                                                g0, be0, g1, be1, g2, be2, Hflat);
    fc_qk_kernel<<<ROWS/16, 256, 0, stream>>>(Hflat, fc_wT, fc_b, g3, be3,
                                              q_wT, q_b, k_wT, k_b, q_ws, k_ws);
    qk_sample_kernel<<<BATCH*NUM_NODES, 256, 0, stream>>>(q_ws, k_ws, idx_g, M_ws);
    topk_kernel<<<BATCH*NHEAD, 256, 0, stream>>>(M_ws, Mtop, inv);
    attn_kernel<<<BATCH*NHEAD*UTOP, 256, 0, stream>>>(q_ws, k_ws, Mtop, attn_ws);
    combine_kernel<<<BATCH*NUM_NODES, 256, 0, stream>>>(attn_ws, inv, out);
}

// Round 4
// 266.272 us; speedup vs baseline: 1.0920x; 1.0621x over previous
//
#include <hip/hip_runtime.h>
#include <math.h>

#define NUM_NODES 2048
#define BATCH 2
#define NHEAD 8
#define SEQ 168
#define HID 256
#define DHEAD 32
#define UPART 80
#define UTOP 40
#define L0C 81
#define L1C 39
#define L2C 19
#define C0 8
#define C1 16
#define C2 32
#define FCIN 608   // 32*19
#define ROWS 4096  // BATCH*NUM_NODES

// ---------------- Kernel 0: transpose the three weight matrices ----------------
__global__ __launch_bounds__(256) void transpose3_kernel(
    const float* __restrict__ fc_w, const float* __restrict__ q_w, const float* __restrict__ k_w,
    float* __restrict__ fc_wT, float* __restrict__ q_wT, float* __restrict__ k_wT)
{
    __shared__ float t[32][33];
    const int z = blockIdx.z;
    const float* in = (z == 0) ? fc_w : ((z == 1) ? q_w : k_w);
    float* out      = (z == 0) ? fc_wT : ((z == 1) ? q_wT : k_wT);
    const int M = 256;                    // rows of in
    const int N = (z == 0) ? FCIN : HID;  // cols of in
    const int bx = blockIdx.x * 32;       // col tile of in
    const int by = blockIdx.y * 32;       // row tile of in
    if (bx >= N) return;
    const int tx = threadIdx.x & 31, ty0 = threadIdx.x >> 5;
    for (int i = ty0; i < 32; i += 8) {
        int r = by + i, c = bx + tx;
        if (r < M && c < N) t[i][tx] = in[(size_t)r * N + c];
    }
    __syncthreads();
    for (int i = ty0; i < 32; i += 8) {
        int r = bx + i, c = by + tx;      // out is N x M
        if (r < N && c < M) out[(size_t)r * M + c] = t[tx][i];
    }
}

// ---------------- Kernel 1: conv chain (conv+relu+LN x3) ----------------
__global__ __launch_bounds__(128) void conv_chain_kernel(
    const float* __restrict__ x,
    const float* __restrict__ w0, const float* __restrict__ b0,
    const float* __restrict__ w1, const float* __restrict__ b1,
    const float* __restrict__ w2, const float* __restrict__ b2,
    const float* __restrict__ g0, const float* __restrict__ be0,
    const float* __restrict__ g1, const float* __restrict__ be1,
    const float* __restrict__ g2, const float* __restrict__ be2,
    float* __restrict__ Hout)
{
    __shared__ float xs[SEQ];
    __shared__ float h0[C0][L0C];
    __shared__ float h1[C1][L1C];
    __shared__ float h2[C2][L2C];
    __shared__ float w0s[C0*7];
    __shared__ float w1s[C1*C0*5];
    __shared__ float w2s[C2*C1*3];

    const int row = blockIdx.x;
    const int tid = threadIdx.x;

    for (int i = tid; i < SEQ; i += 128) xs[i] = x[row*SEQ + i];
    for (int i = tid; i < C0*7; i += 128) w0s[i] = w0[i];
    for (int i = tid; i < C1*C0*5; i += 128) w1s[i] = w1[i];
    for (int i = tid; i < C2*C1*3; i += 128) w2s[i] = w2[i];
    __syncthreads();

    for (int idx = tid; idx < C0*L0C; idx += 128) {
        int c = idx / L0C, t = idx % L0C;
        float acc = b0[c];
        #pragma unroll
        for (int j = 0; j < 7; ++j) acc += w0s[c*7+j] * xs[2*t+j];
        h0[c][t] = fmaxf(acc, 0.f);
    }
    __syncthreads();
    {
        int c = tid >> 4, lane = tid & 15;
        float s = 0.f, s2 = 0.f;
        for (int t = lane; t < L0C; t += 16) { float v = h0[c][t]; s += v; s2 += v*v; }
        #pragma unroll
        for (int m = 8; m >= 1; m >>= 1) { s += __shfl_xor(s, m); s2 += __shfl_xor(s2, m); }
        float mean = s / (float)L0C;
        float inv = rsqrtf(s2 / (float)L0C - mean*mean + 1e-5f);
        for (int t = lane; t < L0C; t += 16)
            h0[c][t] = (h0[c][t] - mean) * inv * g0[t] + be0[t];
    }
    __syncthreads();
    for (int idx = tid; idx < C1*L1C; idx += 128) {
        int c = idx / L1C, t = idx % L1C;
        float acc = b1[c];
        for (int ci = 0; ci < C0; ++ci) {
            #pragma unroll
            for (int j = 0; j < 5; ++j) acc += w1s[(c*C0+ci)*5+j] * h0[ci][2*t+j];
        }
        h1[c][t] = fmaxf(acc, 0.f);
    }
    __syncthreads();
    {
        int c = tid >> 3, lane = tid & 7;
        float s = 0.f, s2 = 0.f;
        for (int t = lane; t < L1C; t += 8) { float v = h1[c][t]; s += v; s2 += v*v; }
        #pragma unroll
        for (int m = 4; m >= 1; m >>= 1) { s += __shfl_xor(s, m); s2 += __shfl_xor(s2, m); }
        float mean = s / (float)L1C;
        float inv = rsqrtf(s2 / (float)L1C - mean*mean + 1e-5f);
        for (int t = lane; t < L1C; t += 8)
            h1[c][t] = (h1[c][t] - mean) * inv * g1[t] + be1[t];
    }
    __syncthreads();
    for (int idx = tid; idx < C2*L2C; idx += 128) {
        int c = idx / L2C, t = idx % L2C;
        float acc = b2[c];
        for (int ci = 0; ci < C1; ++ci) {
            #pragma unroll
            for (int j = 0; j < 3; ++j) acc += w2s[(c*C1+ci)*3+j] * h1[ci][2*t+j];
        }
        h2[c][t] = fmaxf(acc, 0.f);
    }
    __syncthreads();
    {
        int c = tid >> 2, lane = tid & 3;
        float s = 0.f, s2 = 0.f;
        for (int t = lane; t < L2C; t += 4) { float v = h2[c][t]; s += v; s2 += v*v; }
        #pragma unroll
        for (int m = 2; m >= 1; m >>= 1) { s += __shfl_xor(s, m); s2 += __shfl_xor(s2, m); }
        float mean = s / (float)L2C;
        float inv = rsqrtf(s2 / (float)L2C - mean*mean + 1e-5f);
        for (int t = lane; t < L2C; t += 4)
            h2[c][t] = (h2[c][t] - mean) * inv * g2[t] + be2[t];
    }
    __syncthreads();
    for (int i = tid; i < FCIN; i += 128)
        Hout[(size_t)row*FCIN + i] = h2[i / L2C][i % L2C];
}

// ---------------- Kernel 2: fc+relu+LN3 + q,k projections ----------------
// Block: 8 rows x 256 cols, 512 threads = 8 waves = 2 row-halves x 4 k-quarters.
// Grid 512 -> 2 blocks/CU, 16 waves/CU (4/SIMD) for latency hiding.
__global__ __launch_bounds__(512) void fc_qk_kernel(
    const float* __restrict__ Hin,
    const float* __restrict__ fc_wT, const float* __restrict__ fc_b,
    const float* __restrict__ g3, const float* __restrict__ be3,
    const float* __restrict__ q_wT, const float* __restrict__ q_b,
    const float* __restrict__ k_wT, const float* __restrict__ k_b,
    float* __restrict__ q_out, float* __restrict__ k_out)
{
    __shared__ float part[3][8][HID];  // 24KB: partials from kh=1..3 waves
    __shared__ float hm[8][HID];       // 8KB: post-LN activations

    const int tid  = threadIdx.x;
    const int lane = tid & 63;
    const int wave = tid >> 6;
    const int rh   = __builtin_amdgcn_readfirstlane(wave >> 2);  // row half 0/1
    const int kh   = __builtin_amdgcn_readfirstlane(wave & 3);   // k quarter 0..3
    const int c0   = lane * 4;                                   // 4 contiguous cols
    const int r0   = blockIdx.x * 8;
    const int rbase = __builtin_amdgcn_readfirstlane(r0 + rh * 4);

    float4 acc[4];

    // ---------- fc partial over this wave's k-quarter ----------
    #pragma unroll
    for (int r = 0; r < 4; ++r) acc[r] = make_float4(0.f, 0.f, 0.f, 0.f);
    {
        const int kbeg = kh * (FCIN/4), kend = kbeg + FCIN/4;
        for (int k = kbeg; k < kend; k += 4) {
            float4 w0 = *(const float4*)(fc_wT + (size_t)(k+0)*HID + c0);
            float4 w1 = *(const float4*)(fc_wT + (size_t)(k+1)*HID + c0);
            float4 w2 = *(const float4*)(fc_wT + (size_t)(k+2)*HID + c0);
            float4 w3 = *(const float4*)(fc_wT + (size_t)(k+3)*HID + c0);
            #pragma unroll
            for (int r = 0; r < 4; ++r) {
                float4 h4 = *(const float4*)(Hin + (size_t)(rbase + r)*FCIN + k);
                acc[r].x += h4.x*w0.x + h4.y*w1.x + h4.z*w2.x + h4.w*w3.x;
                acc[r].y += h4.x*w0.y + h4.y*w1.y + h4.z*w2.y + h4.w*w3.y;
                acc[r].z += h4.x*w0.z + h4.y*w1.z + h4.z*w2.z + h4.w*w3.z;
                acc[r].w += h4.x*w0.w + h4.y*w1.w + h4.z*w2.w + h4.w*w3.w;
            }
        }
    }
    if (kh != 0) {
        #pragma unroll
        for (int r = 0; r < 4; ++r) *(float4*)&part[kh-1][rh*4 + r][c0] = acc[r];
    }
    __syncthreads();   // S1

    // ---------- reduce + bias + relu + LN3 -> hm (kh==0 waves) ----------
    if (kh == 0) {
        float4 b4 = *(const float4*)(fc_b + c0);
        float4 gg = *(const float4*)(g3 + c0);
        float4 bb = *(const float4*)(be3 + c0);
        #pragma unroll
        for (int r = 0; r < 4; ++r) {
            const int row = rh*4 + r;
            float4 p0 = *(const float4*)&part[0][row][c0];
            float4 p1 = *(const float4*)&part[1][row][c0];
            float4 p2 = *(const float4*)&part[2][row][c0];
            float e0 = fmaxf(acc[r].x + p0.x + p1.x + p2.x + b4.x, 0.f);
            float e1 = fmaxf(acc[r].y + p0.y + p1.y + p2.y + b4.y, 0.f);
            float e2 = fmaxf(acc[r].z + p0.z + p1.z + p2.z + b4.z, 0.f);
            float e3 = fmaxf(acc[r].w + p0.w + p1.w + p2.w + b4.w, 0.f);
            float s  = e0 + e1 + e2 + e3;
            float s2 = e0*e0 + e1*e1 + e2*e2 + e3*e3;
            #pragma unroll
            for (int m = 32; m >= 1; m >>= 1) { s += __shfl_xor(s, m); s2 += __shfl_xor(s2, m); }
            float mean = s * (1.f/256.f);
            float inv  = rsqrtf(s2 * (1.f/256.f) - mean*mean + 1e-5f);
            float4 o;
            o.x = (e0 - mean) * inv * gg.x + bb.x;
            o.y = (e1 - mean) * inv * gg.y + bb.y;
            o.z = (e2 - mean) * inv * gg.z + bb.z;
            o.w = (e3 - mean) * inv * gg.w + bb.w;
            *(float4*)&hm[row][c0] = o;
        }
    }
    __syncthreads();   // S2

    // ---------- q projection ----------
    #pragma unroll
    for (int r = 0; r < 4; ++r) acc[r] = make_float4(0.f, 0.f, 0.f, 0.f);
    {
        const int kbeg = kh * (HID/4), kend = kbeg + HID/4;
        for (int k = kbeg; k < kend; k += 4) {
            float4 w0 = *(const float4*)(q_wT + (size_t)(k+0)*HID + c0);
            float4 w1 = *(const float4*)(q_wT + (size_t)(k+1)*HID + c0);
            float4 w2 = *(const float4*)(q_wT + (size_t)(k+2)*HID + c0);
            float4 w3 = *(const float4*)(q_wT + (size_t)(k+3)*HID + c0);
            #pragma unroll
            for (int r = 0; r < 4; ++r) {
                float4 h4 = *(const float4*)&hm[rh*4 + r][k];
                acc[r].x += h4.x*w0.x + h4.y*w1.x + h4.z*w2.x + h4.w*w3.x;
                acc[r].y += h4.x*w0.y + h4.y*w1.y + h4.z*w2.y + h4.w*w3.y;
                acc[r].z += h4.x*w0.z + h4.y*w1.z + h4.z*w2.z + h4.w*w3.z;
                acc[r].w += h4.x*w0.w + h4.y*w1.w + h4.z*w2.w + h4.w*w3.w;
            }
        }
    }
    if (kh != 0) {
        #pragma unroll
        for (int r = 0; r < 4; ++r) *(float4*)&part[kh-1][rh*4 + r][c0] = acc[r];
    }
    __syncthreads();   // S3
    if (kh == 0) {
        float4 b4 = *(const float4*)(q_b + c0);
        #pragma unroll
        for (int r = 0; r < 4; ++r) {
            const int row = rh*4 + r;
            float4 p0 = *(const float4*)&part[0][row][c0];
            float4 p1 = *(const float4*)&part[1][row][c0];
            float4 p2 = *(const float4*)&part[2][row][c0];
            float4 o;
            o.x = acc[r].x + p0.x + p1.x + p2.x + b4.x;
            o.y = acc[r].y + p0.y + p1.y + p2.y + b4.y;
            o.z = acc[r].z + p0.z + p1.z + p2.z + b4.z;
            o.w = acc[r].w + p0.w + p1.w + p2.w + b4.w;
            *(float4*)(q_out + (size_t)(r0 + row)*HID + c0) = o;
        }
    }

    // ---------- k projection (compute first; barrier before rewriting part) ----------
    #pragma unroll
    for (int r = 0; r < 4; ++r) acc[r] = make_float4(0.f, 0.f, 0.f, 0.f);
    {
        const int kbeg = kh * (HID/4), kend = kbeg + HID/4;
        for (int k = kbeg; k < kend; k += 4) {
            float4 w0 = *(const float4*)(k_wT + (size_t)(k+0)*HID + c0);
            float4 w1 = *(const float4*)(k_wT + (size_t)(k+1)*HID + c0);
            float4 w2 = *(const float4*)(k_wT + (size_t)(k+2)*HID + c0);
            float4 w3 = *(const float4*)(k_wT + (size_t)(k+3)*HID + c0);
            #pragma unroll
            for (int r = 0; r < 4; ++r) {
                float4 h4 = *(const float4*)&hm[rh*4 + r][k];
                acc[r].x += h4.x*w0.x + h4.y*w1.x + h4.z*w2.x + h4.w*w3.x;
                acc[r].y += h4.x*w0.y + h4.y*w1.y + h4.z*w2.y + h4.w*w3.y;
                acc[r].z += h4.x*w0.z + h4.y*w1.z + h4.z*w2.z + h4.w*w3.z;
                acc[r].w += h4.x*w0.w + h4.y*w1.w + h4.z*w2.w + h4.w*w3.w;
            }
        }
    }
    __syncthreads();   // S4: kh0 finished reading q partials before part rewrite
    if (kh != 0) {
        #pragma unroll
        for (int r = 0; r < 4; ++r) *(float4*)&part[kh-1][rh*4 + r][c0] = acc[r];
    }
    __syncthreads();   // S5
    if (kh == 0) {
        float4 b4 = *(const float4*)(k_b + c0);
        #pragma unroll
        for (int r = 0; r < 4; ++r) {
            const int row = rh*4 + r;
            float4 p0 = *(const float4*)&part[0][row][c0];
            float4 p1 = *(const float4*)&part[1][row][c0];
            float4 p2 = *(const float4*)&part[2][row][c0];
            float4 o;
            o.x = acc[r].x + p0.x + p1.x + p2.x + b4.x;
            o.y = acc[r].y + p0.y + p1.y + p2.y + b4.y;
            o.z = acc[r].z + p0.z + p1.z + p2.z + b4.z;
            o.w = acc[r].w + p0.w + p1.w + p2.w + b4.w;
            *(float4*)(k_out + (size_t)(r0 + row)*HID + c0) = o;
        }
    }
}

// ---------------- Kernel 3: QK_sample + M ----------------
__global__ __launch_bounds__(256) void qk_sample_kernel(
    const float* __restrict__ q, const float* __restrict__ k,
    const int* __restrict__ idx_g, float* __restrict__ M)
{
    __shared__ int sidx[UPART];
    __shared__ float qrow[HID];
    __shared__ float qk[NHEAD][UPART];
    const int bl = blockIdx.x;            // b*2048 + l
    const int b = bl >> 11, l = bl & (NUM_NODES-1);
    const int tid = threadIdx.x;
    if (tid < UPART) sidx[tid] = idx_g[l*UPART + tid];
    qrow[tid] = q[(size_t)bl*HID + tid];
    __syncthreads();
    for (int task = tid; task < NHEAD*UPART; task += 256) {
        int h = task / UPART, s = task % UPART;
        const float4* kp = (const float4*)(k + (size_t)(b*NUM_NODES + sidx[s])*HID + h*DHEAD);
        const float4* qp = (const float4*)(qrow + h*DHEAD);
        float acc = 0.f;
        #pragma unroll
        for (int d4 = 0; d4 < 8; ++d4) {
            float4 kv = kp[d4], qv = qp[d4];
            acc += qv.x*kv.x + qv.y*kv.y + qv.z*kv.z + qv.w*kv.w;
        }
        qk[h][s] = acc;
    }
    __syncthreads();
    if (tid < NHEAD) {
        float mx = -INFINITY, sm = 0.f;
        for (int s = 0; s < UPART; ++s) { float v = qk[tid][s]; mx = fmaxf(mx, v); sm += v; }
        M[(size_t)(b*NHEAD + tid)*NUM_NODES + l] = mx - sm / (float)NUM_NODES;
    }
}

// ---------------- fill inv with -1 ----------------
__global__ void fill_inv_kernel(int* __restrict__ inv)
{
    inv[blockIdx.x*256 + threadIdx.x] = -1;
}

// ---------------- Kernel 4: top-40 per (b,h), tie-break = smaller index ----------------
__global__ __launch_bounds__(256) void topk_kernel(
    const float* __restrict__ M, int* __restrict__ Mtop, int* __restrict__ inv)
{
    __shared__ float Ms[NUM_NODES];
    __shared__ float rv[4];
    __shared__ int ri[4];
    const int bh = blockIdx.x;  // b*8+h
    const int b = bh >> 3, h = bh & 7;
    const int tid = threadIdx.x;
    for (int i = tid; i < NUM_NODES; i += 256) Ms[i] = M[(size_t)bh*NUM_NODES + i];
    __syncthreads();
    for (int u = 0; u < UTOP; ++u) {
        float bv = -INFINITY; int bi = NUM_NODES;
        for (int i = tid; i < NUM_NODES; i += 256) {
            float v = Ms[i];
            if (v > bv || (v == bv && i < bi)) { bv = v; bi = i; }
        }
        #pragma unroll
        for (int m = 32; m >= 1; m >>= 1) {
            float ov = __shfl_xor(bv, m); int oi = __shfl_xor(bi, m);
            if (ov > bv || (ov == bv && oi < bi)) { bv = ov; bi = oi; }
        }
        if ((tid & 63) == 0) { rv[tid >> 6] = bv; ri[tid >> 6] = bi; }
        __syncthreads();
        if (tid == 0) {
            float fv = rv[0]; int fi = ri[0];
            #pragma unroll
            for (int w = 1; w < 4; ++w) {
                if (rv[w] > fv || (rv[w] == fv && ri[w] < fi)) { fv = rv[w]; fi = ri[w]; }
            }
            Mtop[bh*UTOP + u] = fi;
            inv[(size_t)(b*NUM_NODES + fi)*NHEAD + h] = u;
            Ms[fi] = -INFINITY;
        }
        __syncthreads();
    }
}

// ---------------- Kernel 5: scores + softmax + threshold ----------------
__global__ __launch_bounds__(256) void attn_kernel(
    const float* __restrict__ q, const float* __restrict__ k,
    const int* __restrict__ Mtop, float* __restrict__ attn)
{
    __shared__ float qsel[DHEAD];
    __shared__ float sc[NUM_NODES];
    __shared__ float red[8];
    const int blk = blockIdx.x;   // (b*8+h)*40+u
    const int bh = blk / UTOP, u = blk % UTOP;
    const int b = bh >> 3, h = bh & 7;
    const int tid = threadIdx.x;
    const int lsel = Mtop[bh*UTOP + u];
    if (tid < DHEAD) qsel[tid] = q[(size_t)(b*NUM_NODES + lsel)*HID + h*DHEAD + tid];
    __syncthreads();
    const float scale = 0.17677669529663687f; // 1/sqrt(32)
    float lmax = -INFINITY;
    for (int j = tid; j < NUM_NODES; j += 256) {
        const float4* kp = (const float4*)(k + (size_t)(b*NUM_NODES + j)*HID + h*DHEAD);
        const float4* qp = (const float4*)qsel;
        float acc = 0.f;
        #pragma unroll
        for (int d4 = 0; d4 < 8; ++d4) {
            float4 kv = kp[d4], qv = qp[d4];
            acc += qv.x*kv.x + qv.y*kv.y + qv.z*kv.z + qv.w*kv.w;
        }
        acc *= scale;
        sc[j] = acc;
        lmax = fmaxf(lmax, acc);
    }
    #pragma unroll
    for (int m = 32; m >= 1; m >>= 1) lmax = fmaxf(lmax, __shfl_xor(lmax, m));
    if ((tid & 63) == 0) red[tid >> 6] = lmax;
    __syncthreads();
    const float gmax = fmaxf(fmaxf(red[0], red[1]), fmaxf(red[2], red[3]));
    float lsum = 0.f;
    for (int j = tid; j < NUM_NODES; j += 256) {
        float e = expf(sc[j] - gmax);
        sc[j] = e;
        lsum += e;
    }
    #pragma unroll
    for (int m = 32; m >= 1; m >>= 1) lsum += __shfl_xor(lsum, m);
    if ((tid & 63) == 0) red[4 + (tid >> 6)] = lsum;
    __syncthreads();
    const float rinv = 1.0f / (red[4] + red[5] + red[6] + red[7]);
    const float thr = 1.0f / (float)NUM_NODES;
    for (int j4 = tid; j4 < NUM_NODES/4; j4 += 256) {
        float4 v;
        v.x = sc[j4*4+0] * rinv; if (v.x < thr) v.x = 0.f;
        v.y = sc[j4*4+1] * rinv; if (v.y < thr) v.y = 0.f;
        v.z = sc[j4*4+2] * rinv; if (v.z < thr) v.z = 0.f;
        v.w = sc[j4*4+3] * rinv; if (v.w < thr) v.w = 0.f;
        *(float4*)(attn + (size_t)blk*NUM_NODES + j4*4) = v;
    }
}

// ---------------- Kernel 6: combine heads -> output ----------------
__global__ __launch_bounds__(256) void combine_kernel(
    const float* __restrict__ attn, const int* __restrict__ inv,
    float* __restrict__ out)
{
    __shared__ int us[NHEAD];
    const int bl = blockIdx.x;  // b*2048+l
    const int b = bl >> 11;
    const int tid = threadIdx.x;
    if (tid < NHEAD) us[tid] = inv[(size_t)bl*NHEAD + tid];
    __syncthreads();
    const size_t outbase = (size_t)bl * NUM_NODES;
    for (int j4 = tid; j4 < NUM_NODES/4; j4 += 256) {
        float4 s = make_float4(0.f, 0.f, 0.f, 0.f);
        #pragma unroll
        for (int h = 0; h < NHEAD; ++h) {
            int u = us[h];
            if (u >= 0) {
                float4 a = *(const float4*)(attn + (size_t)((b*NHEAD + h)*UTOP + u)*NUM_NODES + j4*4);
                s.x += a.x; s.y += a.y; s.z += a.z; s.w += a.w;
            }
        }
        s.x *= 0.125f; s.y *= 0.125f; s.z *= 0.125f; s.w *= 0.125f;
        *(float4*)(out + outbase + j4*4) = s;
    }
}

extern "C" void kernel_launch(void* const* d_in, const int* in_sizes, int n_in,
                              void* d_out, int out_size, void* d_ws, size_t ws_size,
                              hipStream_t stream) {
    const float* x      = (const float*)d_in[0];
    const float* w0     = (const float*)d_in[1];
    const float* b0     = (const float*)d_in[2];
    const float* w1     = (const float*)d_in[3];
    const float* b1     = (const float*)d_in[4];
    const float* w2     = (const float*)d_in[5];
    const float* b2     = (const float*)d_in[6];
    const float* g0     = (const float*)d_in[7];
    const float* be0    = (const float*)d_in[8];
    const float* g1     = (const float*)d_in[9];
    const float* be1    = (const float*)d_in[10];
    const float* g2     = (const float*)d_in[11];
    const float* be2    = (const float*)d_in[12];
    const float* g3     = (const float*)d_in[13];
    const float* be3    = (const float*)d_in[14];
    const float* fc_w   = (const float*)d_in[15];
    const float* fc_b   = (const float*)d_in[16];
    const float* q_w    = (const float*)d_in[17];
    const float* q_b    = (const float*)d_in[18];
    const float* k_w    = (const float*)d_in[19];
    const float* k_b    = (const float*)d_in[20];
    const int* idx_g    = (const int*)d_in[21];
    float* out = (float*)d_out;

    float* Hflat   = (float*)d_ws;                       // 4096*608
    float* q_ws    = Hflat + (size_t)ROWS*FCIN;          // 4096*256
    float* k_ws    = q_ws + (size_t)ROWS*HID;            // 4096*256
    float* M_ws    = k_ws + (size_t)ROWS*HID;            // 2*8*2048
    float* attn_ws = M_ws + (size_t)BATCH*NHEAD*NUM_NODES;   // 2*8*40*2048
    int*   Mtop    = (int*)(attn_ws + (size_t)BATCH*NHEAD*UTOP*NUM_NODES); // 640
    int*   inv     = Mtop + BATCH*NHEAD*UTOP;            // 2*2048*8
    float* fc_wT   = (float*)(inv + (size_t)BATCH*NUM_NODES*NHEAD); // 608*256
    float* q_wT    = fc_wT + (size_t)FCIN*HID;           // 256*256
    float* k_wT    = q_wT + (size_t)HID*HID;             // 256*256

    fill_inv_kernel<<<(BATCH*NUM_NODES*NHEAD)/256, 256, 0, stream>>>(inv);
    {
        dim3 tgrid((FCIN + 31)/32, (HID + 31)/32, 3);
        transpose3_kernel<<<tgrid, 256, 0, stream>>>(fc_w, q_w, k_w, fc_wT, q_wT, k_wT);
    }
    conv_chain_kernel<<<ROWS, 128, 0, stream>>>(x, w0, b0, w1, b1, w2, b2,
                                                g0, be0, g1, be1, g2, be2, Hflat);
    fc_qk_kernel<<<ROWS/8, 512, 0, stream>>>(Hflat, fc_wT, fc_b, g3, be3,
                                             q_wT, q_b, k_wT, k_b, q_ws, k_ws);
    qk_sample_kernel<<<BATCH*NUM_NODES, 256, 0, stream>>>(q_ws, k_ws, idx_g, M_ws);
    topk_kernel<<<BATCH*NHEAD, 256, 0, stream>>>(M_ws, Mtop, inv);
    attn_kernel<<<BATCH*NHEAD*UTOP, 256, 0, stream>>>(q_ws, k_ws, Mtop, attn_ws);
    combine_kernel<<<BATCH*NUM_NODES, 256, 0, stream>>>(attn_ws, inv, out);
}

// Round 5
// 248.901 us; speedup vs baseline: 1.1683x; 1.0698x over previous
//
#include <hip/hip_runtime.h>
#include <math.h>

#define NUM_NODES 2048
#define BATCH 2
#define NHEAD 8
#define SEQ 168
#define HID 256
#define DHEAD 32
#define UPART 80
#define UTOP 40
#define L0C 81
#define L1C 39
#define L2C 19
#define C0 8
#define C1 16
#define C2 32
#define FCIN 608   // 32*19
#define ROWS 4096  // BATCH*NUM_NODES

// ---------------- Kernel 0: transpose the three weight matrices ----------------
__global__ __launch_bounds__(256) void transpose3_kernel(
    const float* __restrict__ fc_w, const float* __restrict__ q_w, const float* __restrict__ k_w,
    float* __restrict__ fc_wT, float* __restrict__ q_wT, float* __restrict__ k_wT)
{
    __shared__ float t[32][33];
    const int z = blockIdx.z;
    const float* in = (z == 0) ? fc_w : ((z == 1) ? q_w : k_w);
    float* out      = (z == 0) ? fc_wT : ((z == 1) ? q_wT : k_wT);
    const int M = 256;                    // rows of in
    const int N = (z == 0) ? FCIN : HID;  // cols of in
    const int bx = blockIdx.x * 32;       // col tile of in
    const int by = blockIdx.y * 32;       // row tile of in
    if (bx >= N) return;
    const int tx = threadIdx.x & 31, ty0 = threadIdx.x >> 5;
    for (int i = ty0; i < 32; i += 8) {
        int r = by + i, c = bx + tx;
        if (r < M && c < N) t[i][tx] = in[(size_t)r * N + c];
    }
    __syncthreads();
    for (int i = ty0; i < 32; i += 8) {
        int r = bx + i, c = by + tx;      // out is N x M
        if (r < N && c < M) out[(size_t)r * M + c] = t[tx][i];
    }
}

// ---------------- Kernel 1: conv chain (conv+relu+LN x3) ----------------
__global__ __launch_bounds__(128) void conv_chain_kernel(
    const float* __restrict__ x,
    const float* __restrict__ w0, const float* __restrict__ b0,
    const float* __restrict__ w1, const float* __restrict__ b1,
    const float* __restrict__ w2, const float* __restrict__ b2,
    const float* __restrict__ g0, const float* __restrict__ be0,
    const float* __restrict__ g1, const float* __restrict__ be1,
    const float* __restrict__ g2, const float* __restrict__ be2,
    float* __restrict__ Hout)
{
    __shared__ float xs[SEQ];
    __shared__ float h0[C0][L0C];
    __shared__ float h1[C1][L1C];
    __shared__ float h2[C2][L2C];
    __shared__ float w0s[C0*7];
    __shared__ float w1s[C1*C0*5];
    __shared__ float w2s[C2*C1*3];

    const int row = blockIdx.x;
    const int tid = threadIdx.x;

    for (int i = tid; i < SEQ; i += 128) xs[i] = x[row*SEQ + i];
    for (int i = tid; i < C0*7; i += 128) w0s[i] = w0[i];
    for (int i = tid; i < C1*C0*5; i += 128) w1s[i] = w1[i];
    for (int i = tid; i < C2*C1*3; i += 128) w2s[i] = w2[i];
    __syncthreads();

    for (int idx = tid; idx < C0*L0C; idx += 128) {
        int c = idx / L0C, t = idx % L0C;
        float acc = b0[c];
        #pragma unroll
        for (int j = 0; j < 7; ++j) acc += w0s[c*7+j] * xs[2*t+j];
        h0[c][t] = fmaxf(acc, 0.f);
    }
    __syncthreads();
    {
        int c = tid >> 4, lane = tid & 15;
        float s = 0.f, s2 = 0.f;
        for (int t = lane; t < L0C; t += 16) { float v = h0[c][t]; s += v; s2 += v*v; }
        #pragma unroll
        for (int m = 8; m >= 1; m >>= 1) { s += __shfl_xor(s, m); s2 += __shfl_xor(s2, m); }
        float mean = s / (float)L0C;
        float inv = rsqrtf(s2 / (float)L0C - mean*mean + 1e-5f);
        for (int t = lane; t < L0C; t += 16)
            h0[c][t] = (h0[c][t] - mean) * inv * g0[t] + be0[t];
    }
    __syncthreads();
    for (int idx = tid; idx < C1*L1C; idx += 128) {
        int c = idx / L1C, t = idx % L1C;
        float acc = b1[c];
        for (int ci = 0; ci < C0; ++ci) {
            #pragma unroll
            for (int j = 0; j < 5; ++j) acc += w1s[(c*C0+ci)*5+j] * h0[ci][2*t+j];
        }
        h1[c][t] = fmaxf(acc, 0.f);
    }
    __syncthreads();
    {
        int c = tid >> 3, lane = tid & 7;
        float s = 0.f, s2 = 0.f;
        for (int t = lane; t < L1C; t += 8) { float v = h1[c][t]; s += v; s2 += v*v; }
        #pragma unroll
        for (int m = 4; m >= 1; m >>= 1) { s += __shfl_xor(s, m); s2 += __shfl_xor(s2, m); }
        float mean = s / (float)L1C;
        float inv = rsqrtf(s2 / (float)L1C - mean*mean + 1e-5f);
        for (int t = lane; t < L1C; t += 8)
            h1[c][t] = (h1[c][t] - mean) * inv * g1[t] + be1[t];
    }
    __syncthreads();
    for (int idx = tid; idx < C2*L2C; idx += 128) {
        int c = idx / L2C, t = idx % L2C;
        float acc = b2[c];
        for (int ci = 0; ci < C1; ++ci) {
            #pragma unroll
            for (int j = 0; j < 3; ++j) acc += w2s[(c*C1+ci)*3+j] * h1[ci][2*t+j];
        }
        h2[c][t] = fmaxf(acc, 0.f);
    }
    __syncthreads();
    {
        int c = tid >> 2, lane = tid & 3;
        float s = 0.f, s2 = 0.f;
        for (int t = lane; t < L2C; t += 4) { float v = h2[c][t]; s += v; s2 += v*v; }
        #pragma unroll
        for (int m = 2; m >= 1; m >>= 1) { s += __shfl_xor(s, m); s2 += __shfl_xor(s2, m); }
        float mean = s / (float)L2C;
        float inv = rsqrtf(s2 / (float)L2C - mean*mean + 1e-5f);
        for (int t = lane; t < L2C; t += 4)
            h2[c][t] = (h2[c][t] - mean) * inv * g2[t] + be2[t];
    }
    __syncthreads();
    for (int i = tid; i < FCIN; i += 128)
        Hout[(size_t)row*FCIN + i] = h2[i / L2C][i % L2C];
}

// ---------------- Kernel 2: fc+relu+LN3 + q,k projections ----------------
// Block: 16 rows x 256 cols. 512 thr = 8 waves = 2 col-groups(128) x 4 k-quarters.
// Lane owns 2 cols (float2 weight loads); R=16 rows per wave -> each weight byte
// feeds 16 rows (register M-reuse), H reads wave-uniform (broadcast). VALU-bound.
__global__ __launch_bounds__(512) void fc_qk_kernel(
    const float* __restrict__ Hin,
    const float* __restrict__ fc_wT, const float* __restrict__ fc_b,
    const float* __restrict__ g3, const float* __restrict__ be3,
    const float* __restrict__ q_wT, const float* __restrict__ q_b,
    const float* __restrict__ k_wT, const float* __restrict__ k_b,
    float* __restrict__ q_out, float* __restrict__ k_out)
{
    __shared__ float part[3][16][HID];  // 48KB: partials from kh=1..3
    __shared__ float hm[16][HID];       // 16KB: activations

    const int tid  = threadIdx.x;
    const int lane = tid & 63;
    const int wave = tid >> 6;
    const int cg   = __builtin_amdgcn_readfirstlane(wave & 1);   // col group 0/1
    const int kh   = __builtin_amdgcn_readfirstlane(wave >> 1);  // k quarter 0..3
    const int c0   = cg * 128 + lane * 2;                        // 2 contiguous cols
    const int r0   = blockIdx.x * 16;

    float2 acc[16];

    // ---------- fc partial over this wave's k-quarter ----------
    #pragma unroll
    for (int r = 0; r < 16; ++r) acc[r] = make_float2(0.f, 0.f);
    {
        const int kbeg = kh * (FCIN/4), kend = kbeg + FCIN/4;
        for (int k = kbeg; k < kend; k += 4) {
            float2 w0 = *(const float2*)(fc_wT + (size_t)(k+0)*HID + c0);
            float2 w1 = *(const float2*)(fc_wT + (size_t)(k+1)*HID + c0);
            float2 w2 = *(const float2*)(fc_wT + (size_t)(k+2)*HID + c0);
            float2 w3 = *(const float2*)(fc_wT + (size_t)(k+3)*HID + c0);
            #pragma unroll
            for (int r = 0; r < 16; ++r) {
                float4 h4 = *(const float4*)(Hin + (size_t)(r0 + r)*FCIN + k);
                acc[r].x += h4.x*w0.x + h4.y*w1.x + h4.z*w2.x + h4.w*w3.x;
                acc[r].y += h4.x*w0.y + h4.y*w1.y + h4.z*w2.y + h4.w*w3.y;
            }
        }
    }
    if (kh != 0) {
        #pragma unroll
        for (int r = 0; r < 16; ++r) *(float2*)&part[kh-1][r][c0] = acc[r];
    }
    __syncthreads();   // S1

    // ---------- reduce + bias + relu -> hm (kh==0 waves) ----------
    if (kh == 0) {
        float2 b2v = *(const float2*)(fc_b + c0);
        #pragma unroll
        for (int r = 0; r < 16; ++r) {
            float2 p0 = *(const float2*)&part[0][r][c0];
            float2 p1 = *(const float2*)&part[1][r][c0];
            float2 p2 = *(const float2*)&part[2][r][c0];
            float2 e;
            e.x = fmaxf(acc[r].x + p0.x + p1.x + p2.x + b2v.x, 0.f);
            e.y = fmaxf(acc[r].y + p0.y + p1.y + p2.y + b2v.y, 0.f);
            *(float2*)&hm[r][c0] = e;
        }
    }
    __syncthreads();   // S2

    // ---------- LN3: wave handles rows 2*wave, 2*wave+1 ----------
    {
        float4 gg = *(const float4*)(g3 + lane*4);
        float4 bb = *(const float4*)(be3 + lane*4);
        #pragma unroll
        for (int rr = 0; rr < 2; ++rr) {
            const int row = wave*2 + rr;
            float4 v = *(const float4*)&hm[row][lane*4];
            float s  = v.x + v.y + v.z + v.w;
            float s2 = v.x*v.x + v.y*v.y + v.z*v.z + v.w*v.w;
            #pragma unroll
            for (int m = 32; m >= 1; m >>= 1) { s += __shfl_xor(s, m); s2 += __shfl_xor(s2, m); }
            float mean = s * (1.f/256.f);
            float inv  = rsqrtf(s2 * (1.f/256.f) - mean*mean + 1e-5f);
            v.x = (v.x - mean) * inv * gg.x + bb.x;
            v.y = (v.y - mean) * inv * gg.y + bb.y;
            v.z = (v.z - mean) * inv * gg.z + bb.z;
            v.w = (v.w - mean) * inv * gg.w + bb.w;
            *(float4*)&hm[row][lane*4] = v;
        }
    }
    __syncthreads();   // S3

    // ---------- q projection ----------
    #pragma unroll
    for (int r = 0; r < 16; ++r) acc[r] = make_float2(0.f, 0.f);
    {
        const int kbeg = kh * (HID/4), kend = kbeg + HID/4;
        for (int k = kbeg; k < kend; k += 4) {
            float2 w0 = *(const float2*)(q_wT + (size_t)(k+0)*HID + c0);
            float2 w1 = *(const float2*)(q_wT + (size_t)(k+1)*HID + c0);
            float2 w2 = *(const float2*)(q_wT + (size_t)(k+2)*HID + c0);
            float2 w3 = *(const float2*)(q_wT + (size_t)(k+3)*HID + c0);
            #pragma unroll
            for (int r = 0; r < 16; ++r) {
                float4 h4 = *(const float4*)&hm[r][k];
                acc[r].x += h4.x*w0.x + h4.y*w1.x + h4.z*w2.x + h4.w*w3.x;
                acc[r].y += h4.x*w0.y + h4.y*w1.y + h4.z*w2.y + h4.w*w3.y;
            }
        }
    }
    if (kh != 0) {
        #pragma unroll
        for (int r = 0; r < 16; ++r) *(float2*)&part[kh-1][r][c0] = acc[r];
    }
    __syncthreads();   // S4
    if (kh == 0) {
        float2 b2v = *(const float2*)(q_b + c0);
        #pragma unroll
        for (int r = 0; r < 16; ++r) {
            float2 p0 = *(const float2*)&part[0][r][c0];
            float2 p1 = *(const float2*)&part[1][r][c0];
            float2 p2 = *(const float2*)&part[2][r][c0];
            float2 o;
            o.x = acc[r].x + p0.x + p1.x + p2.x + b2v.x;
            o.y = acc[r].y + p0.y + p1.y + p2.y + b2v.y;
            *(float2*)(q_out + (size_t)(r0 + r)*HID + c0) = o;
        }
    }

    // ---------- k projection (compute first; barrier before part rewrite) ----------
    #pragma unroll
    for (int r = 0; r < 16; ++r) acc[r] = make_float2(0.f, 0.f);
    {
        const int kbeg = kh * (HID/4), kend = kbeg + HID/4;
        for (int k = kbeg; k < kend; k += 4) {
            float2 w0 = *(const float2*)(k_wT + (size_t)(k+0)*HID + c0);
            float2 w1 = *(const float2*)(k_wT + (size_t)(k+1)*HID + c0);
            float2 w2 = *(const float2*)(k_wT + (size_t)(k+2)*HID + c0);
            float2 w3 = *(const float2*)(k_wT + (size_t)(k+3)*HID + c0);
            #pragma unroll
            for (int r = 0; r < 16; ++r) {
                float4 h4 = *(const float4*)&hm[r][k];
                acc[r].x += h4.x*w0.x + h4.y*w1.x + h4.z*w2.x + h4.w*w3.x;
                acc[r].y += h4.x*w0.y + h4.y*w1.y + h4.z*w2.y + h4.w*w3.y;
            }
        }
    }
    __syncthreads();   // S5: kh0 done reading q partials
    if (kh != 0) {
        #pragma unroll
        for (int r = 0; r < 16; ++r) *(float2*)&part[kh-1][r][c0] = acc[r];
    }
    __syncthreads();   // S6
    if (kh == 0) {
        float2 b2v = *(const float2*)(k_b + c0);
        #pragma unroll
        for (int r = 0; r < 16; ++r) {
            float2 p0 = *(const float2*)&part[0][r][c0];
            float2 p1 = *(const float2*)&part[1][r][c0];
            float2 p2 = *(const float2*)&part[2][r][c0];
            float2 o;
            o.x = acc[r].x + p0.x + p1.x + p2.x + b2v.x;
            o.y = acc[r].y + p0.y + p1.y + p2.y + b2v.y;
            *(float2*)(k_out + (size_t)(r0 + r)*HID + c0) = o;
        }
    }
}

// ---------------- Kernel 3: QK_sample + M ----------------
__global__ __launch_bounds__(256) void qk_sample_kernel(
    const float* __restrict__ q, const float* __restrict__ k,
    const int* __restrict__ idx_g, float* __restrict__ M)
{
    __shared__ int sidx[UPART];
    __shared__ float qrow[HID];
    __shared__ float qk[NHEAD][UPART];
    const int bl = blockIdx.x;            // b*2048 + l
    const int b = bl >> 11, l = bl & (NUM_NODES-1);
    const int tid = threadIdx.x;
    if (tid < UPART) sidx[tid] = idx_g[l*UPART + tid];
    qrow[tid] = q[(size_t)bl*HID + tid];
    __syncthreads();
    for (int task = tid; task < NHEAD*UPART; task += 256) {
        int h = task / UPART, s = task % UPART;
        const float4* kp = (const float4*)(k + (size_t)(b*NUM_NODES + sidx[s])*HID + h*DHEAD);
        const float4* qp = (const float4*)(qrow + h*DHEAD);
        float acc = 0.f;
        #pragma unroll
        for (int d4 = 0; d4 < 8; ++d4) {
            float4 kv = kp[d4], qv = qp[d4];
            acc += qv.x*kv.x + qv.y*kv.y + qv.z*kv.z + qv.w*kv.w;
        }
        qk[h][s] = acc;
    }
    __syncthreads();
    if (tid < NHEAD) {
        float mx = -INFINITY, sm = 0.f;
        for (int s = 0; s < UPART; ++s) { float v = qk[tid][s]; mx = fmaxf(mx, v); sm += v; }
        M[(size_t)(b*NHEAD + tid)*NUM_NODES + l] = mx - sm / (float)NUM_NODES;
    }
}

// ---------------- Kernel 4: top-40 per (b,h), tie-break = smaller index ----------------
__global__ __launch_bounds__(256) void topk_kernel(
    const float* __restrict__ M, int* __restrict__ Mtop)
{
    __shared__ float Ms[NUM_NODES];
    __shared__ float rv[4];
    __shared__ int ri[4];
    const int bh = blockIdx.x;  // b*8+h
    const int tid = threadIdx.x;
    for (int i = tid; i < NUM_NODES; i += 256) Ms[i] = M[(size_t)bh*NUM_NODES + i];
    __syncthreads();
    for (int u = 0; u < UTOP; ++u) {
        float bv = -INFINITY; int bi = NUM_NODES;
        for (int i = tid; i < NUM_NODES; i += 256) {
            float v = Ms[i];
            if (v > bv || (v == bv && i < bi)) { bv = v; bi = i; }
        }
        #pragma unroll
        for (int m = 32; m >= 1; m >>= 1) {
            float ov = __shfl_xor(bv, m); int oi = __shfl_xor(bi, m);
            if (ov > bv || (ov == bv && oi < bi)) { bv = ov; bi = oi; }
        }
        if ((tid & 63) == 0) { rv[tid >> 6] = bv; ri[tid >> 6] = bi; }
        __syncthreads();
        if (tid == 0) {
            float fv = rv[0]; int fi = ri[0];
            #pragma unroll
            for (int w = 1; w < 4; ++w) {
                if (rv[w] > fv || (rv[w] == fv && ri[w] < fi)) { fv = rv[w]; fi = ri[w]; }
            }
            Mtop[bh*UTOP + u] = fi;
            Ms[fi] = -INFINITY;
        }
        __syncthreads();
    }
}

// ---------------- Kernel 5: scores + softmax + threshold ----------------
__global__ __launch_bounds__(256) void attn_kernel(
    const float* __restrict__ q, const float* __restrict__ k,
    const int* __restrict__ Mtop, float* __restrict__ attn)
{
    __shared__ float qsel[DHEAD];
    __shared__ float sc[NUM_NODES];
    __shared__ float red[8];
    const int blk = blockIdx.x;   // (b*8+h)*40+u
    const int bh = blk / UTOP, u = blk % UTOP;
    const int b = bh >> 3, h = bh & 7;
    const int tid = threadIdx.x;
    const int lsel = Mtop[bh*UTOP + u];
    if (tid < DHEAD) qsel[tid] = q[(size_t)(b*NUM_NODES + lsel)*HID + h*DHEAD + tid];
    __syncthreads();
    const float scale = 0.17677669529663687f; // 1/sqrt(32)
    float lmax = -INFINITY;
    for (int j = tid; j < NUM_NODES; j += 256) {
        const float4* kp = (const float4*)(k + (size_t)(b*NUM_NODES + j)*HID + h*DHEAD);
        const float4* qp = (const float4*)qsel;
        float acc = 0.f;
        #pragma unroll
        for (int d4 = 0; d4 < 8; ++d4) {
            float4 kv = kp[d4], qv = qp[d4];
            acc += qv.x*kv.x + qv.y*kv.y + qv.z*kv.z + qv.w*kv.w;
        }
        acc *= scale;
        sc[j] = acc;
        lmax = fmaxf(lmax, acc);
    }
    #pragma unroll
    for (int m = 32; m >= 1; m >>= 1) lmax = fmaxf(lmax, __shfl_xor(lmax, m));
    if ((tid & 63) == 0) red[tid >> 6] = lmax;
    __syncthreads();
    const float gmax = fmaxf(fmaxf(red[0], red[1]), fmaxf(red[2], red[3]));
    float lsum = 0.f;
    for (int j = tid; j < NUM_NODES; j += 256) {
        float e = expf(sc[j] - gmax);
        sc[j] = e;
        lsum += e;
    }
    #pragma unroll
    for (int m = 32; m >= 1; m >>= 1) lsum += __shfl_xor(lsum, m);
    if ((tid & 63) == 0) red[4 + (tid >> 6)] = lsum;
    __syncthreads();
    const float rinv = 1.0f / (red[4] + red[5] + red[6] + red[7]);
    const float thr = 1.0f / (float)NUM_NODES;
    for (int j4 = tid; j4 < NUM_NODES/4; j4 += 256) {
        float4 v;
        v.x = sc[j4*4+0] * rinv; if (v.x < thr) v.x = 0.f;
        v.y = sc[j4*4+1] * rinv; if (v.y < thr) v.y = 0.f;
        v.z = sc[j4*4+2] * rinv; if (v.z < thr) v.z = 0.f;
        v.w = sc[j4*4+3] * rinv; if (v.w < thr) v.w = 0.f;
        *(float4*)(attn + (size_t)blk*NUM_NODES + j4*4) = v;
    }
}

// ---------------- Kernel 6: combine heads -> output (scans Mtop directly) ----------------
__global__ __launch_bounds__(256) void combine_kernel(
    const float* __restrict__ attn, const int* __restrict__ Mtop,
    float* __restrict__ out)
{
    __shared__ int mtops[NHEAD*UTOP];
    __shared__ int us[NHEAD];
    const int bl = blockIdx.x;  // b*2048+l
    const int b = bl >> 11, l = bl & (NUM_NODES-1);
    const int tid = threadIdx.x;
    if (tid < NHEAD) us[tid] = -1;
    for (int i = tid; i < NHEAD*UTOP; i += 256) mtops[i] = Mtop[b*NHEAD*UTOP + i];
    __syncthreads();
    for (int i = tid; i < NHEAD*UTOP; i += 256) {
        if (mtops[i] == l) us[i / UTOP] = i % UTOP;
    }
    __syncthreads();
    const size_t outbase = (size_t)bl * NUM_NODES;
    for (int j4 = tid; j4 < NUM_NODES/4; j4 += 256) {
        float4 s = make_float4(0.f, 0.f, 0.f, 0.f);
        #pragma unroll
        for (int h = 0; h < NHEAD; ++h) {
            int u = us[h];
            if (u >= 0) {
                float4 a = *(const float4*)(attn + (size_t)((b*NHEAD + h)*UTOP + u)*NUM_NODES + j4*4);
                s.x += a.x; s.y += a.y; s.z += a.z; s.w += a.w;
            }
        }
        s.x *= 0.125f; s.y *= 0.125f; s.z *= 0.125f; s.w *= 0.125f;
        *(float4*)(out + outbase + j4*4) = s;
    }
}

extern "C" void kernel_launch(void* const* d_in, const int* in_sizes, int n_in,
                              void* d_out, int out_size, void* d_ws, size_t ws_size,
                              hipStream_t stream) {
    const float* x      = (const float*)d_in[0];
    const float* w0     = (const float*)d_in[1];
    const float* b0     = (const float*)d_in[2];
    const float* w1     = (const float*)d_in[3];
    const float* b1     = (const float*)d_in[4];
    const float* w2     = (const float*)d_in[5];
    const float* b2     = (const float*)d_in[6];
    const float* g0     = (const float*)d_in[7];
    const float* be0    = (const float*)d_in[8];
    const float* g1     = (const float*)d_in[9];
    const float* be1    = (const float*)d_in[10];
    const float* g2     = (const float*)d_in[11];
    const float* be2    = (const float*)d_in[12];
    const float* g3     = (const float*)d_in[13];
    const float* be3    = (const float*)d_in[14];
    const float* fc_w   = (const float*)d_in[15];
    const float* fc_b   = (const float*)d_in[16];
    const float* q_w    = (const float*)d_in[17];
    const float* q_b    = (const float*)d_in[18];
    const float* k_w    = (const float*)d_in[19];
    const float* k_b    = (const float*)d_in[20];
    const int* idx_g    = (const int*)d_in[21];
    float* out = (float*)d_out;

    float* Hflat   = (float*)d_ws;                       // 4096*608
    float* q_ws    = Hflat + (size_t)ROWS*FCIN;          // 4096*256
    float* k_ws    = q_ws + (size_t)ROWS*HID;            // 4096*256
    float* M_ws    = k_ws + (size_t)ROWS*HID;            // 2*8*2048
    float* attn_ws = M_ws + (size_t)BATCH*NHEAD*NUM_NODES;   // 2*8*40*2048
    int*   Mtop    = (int*)(attn_ws + (size_t)BATCH*NHEAD*UTOP*NUM_NODES); // 640
    float* fc_wT   = (float*)(Mtop + BATCH*NHEAD*UTOP);  // 608*256
    float* q_wT    = fc_wT + (size_t)FCIN*HID;           // 256*256
    float* k_wT    = q_wT + (size_t)HID*HID;             // 256*256

    {
        dim3 tgrid((FCIN + 31)/32, (HID + 31)/32, 3);
        transpose3_kernel<<<tgrid, 256, 0, stream>>>(fc_w, q_w, k_w, fc_wT, q_wT, k_wT);
    }
    conv_chain_kernel<<<ROWS, 128, 0, stream>>>(x, w0, b0, w1, b1, w2, b2,
                                                g0, be0, g1, be1, g2, be2, Hflat);
    fc_qk_kernel<<<ROWS/16, 512, 0, stream>>>(Hflat, fc_wT, fc_b, g3, be3,
                                              q_wT, q_b, k_wT, k_b, q_ws, k_ws);
    qk_sample_kernel<<<BATCH*NUM_NODES, 256, 0, stream>>>(q_ws, k_ws, idx_g, M_ws);
    topk_kernel<<<BATCH*NHEAD, 256, 0, stream>>>(M_ws, Mtop);
    attn_kernel<<<BATCH*NHEAD*UTOP, 256, 0, stream>>>(q_ws, k_ws, Mtop, attn_ws);
    combine_kernel<<<BATCH*NUM_NODES, 256, 0, stream>>>(attn_ws, Mtop, out);
}

// Round 6
// 192.749 us; speedup vs baseline: 1.5086x; 1.2913x over previous
//
#include <hip/hip_runtime.h>
#include <math.h>

#define NUM_NODES 2048
#define BATCH 2
#define NHEAD 8
#define SEQ 168
#define HID 256
#define DHEAD 32
#define UPART 80
#define UTOP 40
#define L0C 81
#define L1C 39
#define L2C 19
#define C0 8
#define C1 16
#define C2 32
#define FCIN 608   // 32*19
#define ROWS 4096  // BATCH*NUM_NODES

// ---------------- Kernel 0: transpose the three weight matrices ----------------
__global__ __launch_bounds__(256) void transpose3_kernel(
    const float* __restrict__ fc_w, const float* __restrict__ q_w, const float* __restrict__ k_w,
    float* __restrict__ fc_wT, float* __restrict__ q_wT, float* __restrict__ k_wT)
{
    __shared__ float t[32][33];
    const int z = blockIdx.z;
    const float* in = (z == 0) ? fc_w : ((z == 1) ? q_w : k_w);
    float* out      = (z == 0) ? fc_wT : ((z == 1) ? q_wT : k_wT);
    const int M = 256;                    // rows of in
    const int N = (z == 0) ? FCIN : HID;  // cols of in
    const int bx = blockIdx.x * 32;       // col tile of in
    const int by = blockIdx.y * 32;       // row tile of in
    if (bx >= N) return;
    const int tx = threadIdx.x & 31, ty0 = threadIdx.x >> 5;
    for (int i = ty0; i < 32; i += 8) {
        int r = by + i, c = bx + tx;
        if (r < M && c < N) t[i][tx] = in[(size_t)r * N + c];
    }
    __syncthreads();
    for (int i = ty0; i < 32; i += 8) {
        int r = bx + i, c = by + tx;      // out is N x M
        if (r < N && c < M) out[(size_t)r * M + c] = t[tx][i];
    }
}

// ---------------- Kernel 1: conv chain (conv+relu+LN x3) ----------------
__global__ __launch_bounds__(128) void conv_chain_kernel(
    const float* __restrict__ x,
    const float* __restrict__ w0, const float* __restrict__ b0,
    const float* __restrict__ w1, const float* __restrict__ b1,
    const float* __restrict__ w2, const float* __restrict__ b2,
    const float* __restrict__ g0, const float* __restrict__ be0,
    const float* __restrict__ g1, const float* __restrict__ be1,
    const float* __restrict__ g2, const float* __restrict__ be2,
    float* __restrict__ Hout)
{
    __shared__ float xs[SEQ];
    __shared__ float h0[C0][L0C];
    __shared__ float h1[C1][L1C];
    __shared__ float h2[C2][L2C];
    __shared__ float w0s[C0*7];
    __shared__ float w1s[C1*C0*5];
    __shared__ float w2s[C2*C1*3];

    const int row = blockIdx.x;
    const int tid = threadIdx.x;

    for (int i = tid; i < SEQ; i += 128) xs[i] = x[row*SEQ + i];
    for (int i = tid; i < C0*7; i += 128) w0s[i] = w0[i];
    for (int i = tid; i < C1*C0*5; i += 128) w1s[i] = w1[i];
    for (int i = tid; i < C2*C1*3; i += 128) w2s[i] = w2[i];
    __syncthreads();

    for (int idx = tid; idx < C0*L0C; idx += 128) {
        int c = idx / L0C, t = idx % L0C;
        float acc = b0[c];
        #pragma unroll
        for (int j = 0; j < 7; ++j) acc += w0s[c*7+j] * xs[2*t+j];
        h0[c][t] = fmaxf(acc, 0.f);
    }
    __syncthreads();
    {
        int c = tid >> 4, lane = tid & 15;
        float s = 0.f, s2 = 0.f;
        for (int t = lane; t < L0C; t += 16) { float v = h0[c][t]; s += v; s2 += v*v; }
        #pragma unroll
        for (int m = 8; m >= 1; m >>= 1) { s += __shfl_xor(s, m); s2 += __shfl_xor(s2, m); }
        float mean = s / (float)L0C;
        float inv = rsqrtf(s2 / (float)L0C - mean*mean + 1e-5f);
        for (int t = lane; t < L0C; t += 16)
            h0[c][t] = (h0[c][t] - mean) * inv * g0[t] + be0[t];
    }
    __syncthreads();
    for (int idx = tid; idx < C1*L1C; idx += 128) {
        int c = idx / L1C, t = idx % L1C;
        float acc = b1[c];
        for (int ci = 0; ci < C0; ++ci) {
            #pragma unroll
            for (int j = 0; j < 5; ++j) acc += w1s[(c*C0+ci)*5+j] * h0[ci][2*t+j];
        }
        h1[c][t] = fmaxf(acc, 0.f);
    }
    __syncthreads();
    {
        int c = tid >> 3, lane = tid & 7;
        float s = 0.f, s2 = 0.f;
        for (int t = lane; t < L1C; t += 8) { float v = h1[c][t]; s += v; s2 += v*v; }
        #pragma unroll
        for (int m = 4; m >= 1; m >>= 1) { s += __shfl_xor(s, m); s2 += __shfl_xor(s2, m); }
        float mean = s / (float)L1C;
        float inv = rsqrtf(s2 / (float)L1C - mean*mean + 1e-5f);
        for (int t = lane; t < L1C; t += 8)
            h1[c][t] = (h1[c][t] - mean) * inv * g1[t] + be1[t];
    }
    __syncthreads();
    for (int idx = tid; idx < C2*L2C; idx += 128) {
        int c = idx / L2C, t = idx % L2C;
        float acc = b2[c];
        for (int ci = 0; ci < C1; ++ci) {
            #pragma unroll
            for (int j = 0; j < 3; ++j) acc += w2s[(c*C1+ci)*3+j] * h1[ci][2*t+j];
        }
        h2[c][t] = fmaxf(acc, 0.f);
    }
    __syncthreads();
    {
        int c = tid >> 2, lane = tid & 3;
        float s = 0.f, s2 = 0.f;
        for (int t = lane; t < L2C; t += 4) { float v = h2[c][t]; s += v; s2 += v*v; }
        #pragma unroll
        for (int m = 2; m >= 1; m >>= 1) { s += __shfl_xor(s, m); s2 += __shfl_xor(s2, m); }
        float mean = s / (float)L2C;
        float inv = rsqrtf(s2 / (float)L2C - mean*mean + 1e-5f);
        for (int t = lane; t < L2C; t += 4)
            h2[c][t] = (h2[c][t] - mean) * inv * g2[t] + be2[t];
    }
    __syncthreads();
    for (int i = tid; i < FCIN; i += 128)
        Hout[(size_t)row*FCIN + i] = h2[i / L2C][i % L2C];
}

// ---------------- Kernel 2: fc+relu+LN3 + q,k projections ----------------
__global__ __launch_bounds__(512) void fc_qk_kernel(
    const float* __restrict__ Hin,
    const float* __restrict__ fc_wT, const float* __restrict__ fc_b,
    const float* __restrict__ g3, const float* __restrict__ be3,
    const float* __restrict__ q_wT, const float* __restrict__ q_b,
    const float* __restrict__ k_wT, const float* __restrict__ k_b,
    float* __restrict__ q_out, float* __restrict__ k_out)
{
    __shared__ float part[3][16][HID];  // 48KB: partials from kh=1..3
    __shared__ float hm[16][HID];       // 16KB: activations

    const int tid  = threadIdx.x;
    const int lane = tid & 63;
    const int wave = tid >> 6;
    const int cg   = __builtin_amdgcn_readfirstlane(wave & 1);   // col group 0/1
    const int kh   = __builtin_amdgcn_readfirstlane(wave >> 1);  // k quarter 0..3
    const int c0   = cg * 128 + lane * 2;                        // 2 contiguous cols
    const int r0   = blockIdx.x * 16;

    float2 acc[16];

    // ---------- fc partial over this wave's k-quarter ----------
    #pragma unroll
    for (int r = 0; r < 16; ++r) acc[r] = make_float2(0.f, 0.f);
    {
        const int kbeg = kh * (FCIN/4), kend = kbeg + FCIN/4;
        for (int k = kbeg; k < kend; k += 4) {
            float2 w0 = *(const float2*)(fc_wT + (size_t)(k+0)*HID + c0);
            float2 w1 = *(const float2*)(fc_wT + (size_t)(k+1)*HID + c0);
            float2 w2 = *(const float2*)(fc_wT + (size_t)(k+2)*HID + c0);
            float2 w3 = *(const float2*)(fc_wT + (size_t)(k+3)*HID + c0);
            #pragma unroll
            for (int r = 0; r < 16; ++r) {
                float4 h4 = *(const float4*)(Hin + (size_t)(r0 + r)*FCIN + k);
                acc[r].x += h4.x*w0.x + h4.y*w1.x + h4.z*w2.x + h4.w*w3.x;
                acc[r].y += h4.x*w0.y + h4.y*w1.y + h4.z*w2.y + h4.w*w3.y;
            }
        }
    }
    if (kh != 0) {
        #pragma unroll
        for (int r = 0; r < 16; ++r) *(float2*)&part[kh-1][r][c0] = acc[r];
    }
    __syncthreads();   // S1

    // ---------- reduce + bias + relu -> hm (kh==0 waves) ----------
    if (kh == 0) {
        float2 b2v = *(const float2*)(fc_b + c0);
        #pragma unroll
        for (int r = 0; r < 16; ++r) {
            float2 p0 = *(const float2*)&part[0][r][c0];
            float2 p1 = *(const float2*)&part[1][r][c0];
            float2 p2 = *(const float2*)&part[2][r][c0];
            float2 e;
            e.x = fmaxf(acc[r].x + p0.x + p1.x + p2.x + b2v.x, 0.f);
            e.y = fmaxf(acc[r].y + p0.y + p1.y + p2.y + b2v.y, 0.f);
            *(float2*)&hm[r][c0] = e;
        }
    }
    __syncthreads();   // S2

    // ---------- LN3: wave handles rows 2*wave, 2*wave+1 ----------
    {
        float4 gg = *(const float4*)(g3 + lane*4);
        float4 bb = *(const float4*)(be3 + lane*4);
        #pragma unroll
        for (int rr = 0; rr < 2; ++rr) {
            const int row = wave*2 + rr;
            float4 v = *(const float4*)&hm[row][lane*4];
            float s  = v.x + v.y + v.z + v.w;
            float s2 = v.x*v.x + v.y*v.y + v.z*v.z + v.w*v.w;
            #pragma unroll
            for (int m = 32; m >= 1; m >>= 1) { s += __shfl_xor(s, m); s2 += __shfl_xor(s2, m); }
            float mean = s * (1.f/256.f);
            float inv  = rsqrtf(s2 * (1.f/256.f) - mean*mean + 1e-5f);
            v.x = (v.x - mean) * inv * gg.x + bb.x;
            v.y = (v.y - mean) * inv * gg.y + bb.y;
            v.z = (v.z - mean) * inv * gg.z + bb.z;
            v.w = (v.w - mean) * inv * gg.w + bb.w;
            *(float4*)&hm[row][lane*4] = v;
        }
    }
    __syncthreads();   // S3

    // ---------- q projection ----------
    #pragma unroll
    for (int r = 0; r < 16; ++r) acc[r] = make_float2(0.f, 0.f);
    {
        const int kbeg = kh * (HID/4), kend = kbeg + HID/4;
        for (int k = kbeg; k < kend; k += 4) {
            float2 w0 = *(const float2*)(q_wT + (size_t)(k+0)*HID + c0);
            float2 w1 = *(const float2*)(q_wT + (size_t)(k+1)*HID + c0);
            float2 w2 = *(const float2*)(q_wT + (size_t)(k+2)*HID + c0);
            float2 w3 = *(const float2*)(q_wT + (size_t)(k+3)*HID + c0);
            #pragma unroll
            for (int r = 0; r < 16; ++r) {
                float4 h4 = *(const float4*)&hm[r][k];
                acc[r].x += h4.x*w0.x + h4.y*w1.x + h4.z*w2.x + h4.w*w3.x;
                acc[r].y += h4.x*w0.y + h4.y*w1.y + h4.z*w2.y + h4.w*w3.y;
            }
        }
    }
    if (kh != 0) {
        #pragma unroll
        for (int r = 0; r < 16; ++r) *(float2*)&part[kh-1][r][c0] = acc[r];
    }
    __syncthreads();   // S4
    if (kh == 0) {
        float2 b2v = *(const float2*)(q_b + c0);
        #pragma unroll
        for (int r = 0; r < 16; ++r) {
            float2 p0 = *(const float2*)&part[0][r][c0];
            float2 p1 = *(const float2*)&part[1][r][c0];
            float2 p2 = *(const float2*)&part[2][r][c0];
            float2 o;
            o.x = acc[r].x + p0.x + p1.x + p2.x + b2v.x;
            o.y = acc[r].y + p0.y + p1.y + p2.y + b2v.y;
            *(float2*)(q_out + (size_t)(r0 + r)*HID + c0) = o;
        }
    }

    // ---------- k projection (compute first; barrier before part rewrite) ----------
    #pragma unroll
    for (int r = 0; r < 16; ++r) acc[r] = make_float2(0.f, 0.f);
    {
        const int kbeg = kh * (HID/4), kend = kbeg + HID/4;
        for (int k = kbeg; k < kend; k += 4) {
            float2 w0 = *(const float2*)(k_wT + (size_t)(k+0)*HID + c0);
            float2 w1 = *(const float2*)(k_wT + (size_t)(k+1)*HID + c0);
            float2 w2 = *(const float2*)(k_wT + (size_t)(k+2)*HID + c0);
            float2 w3 = *(const float2*)(k_wT + (size_t)(k+3)*HID + c0);
            #pragma unroll
            for (int r = 0; r < 16; ++r) {
                float4 h4 = *(const float4*)&hm[r][k];
                acc[r].x += h4.x*w0.x + h4.y*w1.x + h4.z*w2.x + h4.w*w3.x;
                acc[r].y += h4.x*w0.y + h4.y*w1.y + h4.z*w2.y + h4.w*w3.y;
            }
        }
    }
    __syncthreads();   // S5: kh0 done reading q partials
    if (kh != 0) {
        #pragma unroll
        for (int r = 0; r < 16; ++r) *(float2*)&part[kh-1][r][c0] = acc[r];
    }
    __syncthreads();   // S6
    if (kh == 0) {
        float2 b2v = *(const float2*)(k_b + c0);
        #pragma unroll
        for (int r = 0; r < 16; ++r) {
            float2 p0 = *(const float2*)&part[0][r][c0];
            float2 p1 = *(const float2*)&part[1][r][c0];
            float2 p2 = *(const float2*)&part[2][r][c0];
            float2 o;
            o.x = acc[r].x + p0.x + p1.x + p2.x + b2v.x;
            o.y = acc[r].y + p0.y + p1.y + p2.y + b2v.y;
            *(float2*)(k_out + (size_t)(r0 + r)*HID + c0) = o;
        }
    }
}

// ---------------- Kernel 3: QK_sample + M ----------------
__global__ __launch_bounds__(256) void qk_sample_kernel(
    const float* __restrict__ q, const float* __restrict__ k,
    const int* __restrict__ idx_g, float* __restrict__ M)
{
    __shared__ int sidx[UPART];
    __shared__ float qrow[HID];
    __shared__ float qk[NHEAD][UPART];
    const int bl = blockIdx.x;            // b*2048 + l
    const int b = bl >> 11, l = bl & (NUM_NODES-1);
    const int tid = threadIdx.x;
    if (tid < UPART) sidx[tid] = idx_g[l*UPART + tid];
    qrow[tid] = q[(size_t)bl*HID + tid];
    __syncthreads();
    for (int task = tid; task < NHEAD*UPART; task += 256) {
        int h = task / UPART, s = task % UPART;
        const float4* kp = (const float4*)(k + (size_t)(b*NUM_NODES + sidx[s])*HID + h*DHEAD);
        const float4* qp = (const float4*)(qrow + h*DHEAD);
        float acc = 0.f;
        #pragma unroll
        for (int d4 = 0; d4 < 8; ++d4) {
            float4 kv = kp[d4], qv = qp[d4];
            acc += qv.x*kv.x + qv.y*kv.y + qv.z*kv.z + qv.w*kv.w;
        }
        qk[h][s] = acc;
    }
    __syncthreads();
    if (tid < NHEAD) {
        float mx = -INFINITY, sm = 0.f;
        for (int s = 0; s < UPART; ++s) { float v = qk[tid][s]; mx = fmaxf(mx, v); sm += v; }
        M[(size_t)(b*NHEAD + tid)*NUM_NODES + l] = mx - sm / (float)NUM_NODES;
    }
}

// ---------------- Kernel 4: top-40 per (b,h) via 4-round radix select ----------------
// Key transform is order-preserving; selection set matches JAX top_k (ties ->
// smaller index). Output order within Mtop is irrelevant: final output depends
// only on the selected SET (each u computes softmax(q[Mtop[u]]·k) independently
// and combine matches by value), so atomic ordering keeps output deterministic.
__global__ __launch_bounds__(256) void topk_kernel(
    const float* __restrict__ M, int* __restrict__ Mtop)
{
    __shared__ unsigned int keys[NUM_NODES];   // 8KB
    __shared__ unsigned int hist[256];         // 1KB
    __shared__ int tiebuf[NUM_NODES];          // 8KB (worst case)
    __shared__ int cnt_gt, cnt_tie;
    __shared__ unsigned int s_prefix;
    __shared__ int s_r;

    const int bh = blockIdx.x;  // b*8+h
    const int tid = threadIdx.x;

    for (int i = tid; i < NUM_NODES; i += 256) {
        unsigned int u = __float_as_uint(M[(size_t)bh*NUM_NODES + i]);
        keys[i] = (u & 0x80000000u) ? ~u : (u | 0x80000000u);
    }
    if (tid == 0) { s_prefix = 0u; s_r = UTOP; cnt_gt = 0; cnt_tie = 0; }
    __syncthreads();

    for (int shift = 24; shift >= 0; shift -= 8) {
        hist[tid] = 0u;                        // 256 threads = 256 bins
        __syncthreads();
        const unsigned int prefix = s_prefix;
        const unsigned int pmask = (shift == 24) ? 0u : ~((1u << (shift + 8)) - 1u);
        for (int i = tid; i < NUM_NODES; i += 256) {
            unsigned int k = keys[i];
            if ((k & pmask) == prefix)
                atomicAdd(&hist[(k >> shift) & 0xFFu], 1u);
        }
        __syncthreads();
        if (tid < 64) {
            // wave 0: suffix-scan 256 bins, 4 per lane, descending bin order
            const int b0 = 255 - tid * 4;
            unsigned int c0 = hist[b0], c1 = hist[b0-1], c2 = hist[b0-2], c3 = hist[b0-3];
            unsigned int gsum = c0 + c1 + c2 + c3;
            unsigned int pre = gsum;
            #pragma unroll
            for (int d = 1; d < 64; d <<= 1) {
                unsigned int o = __shfl_up(pre, d);
                if (tid >= d) pre += o;
            }
            pre -= gsum;   // count of candidates in strictly-higher bins
            const unsigned int r = (unsigned int)s_r;
            unsigned int ca0 = pre, ca1 = ca0 + c0, ca2 = ca1 + c1, ca3 = ca2 + c2;
            if (ca0 < r && r <= ca0 + c0) { s_prefix = prefix | ((unsigned int)(b0  ) << shift); s_r = (int)(r - ca0); }
            if (ca1 < r && r <= ca1 + c1) { s_prefix = prefix | ((unsigned int)(b0-1) << shift); s_r = (int)(r - ca1); }
            if (ca2 < r && r <= ca2 + c2) { s_prefix = prefix | ((unsigned int)(b0-2) << shift); s_r = (int)(r - ca2); }
            if (ca3 < r && r <= ca3 + c3) { s_prefix = prefix | ((unsigned int)(b0-3) << shift); s_r = (int)(r - ca3); }
        }
        __syncthreads();
    }

    const unsigned int P = s_prefix;   // pivot key (40th-largest value)
    const int r = s_r;                 // how many pivot-equal elements to take
    for (int i = tid; i < NUM_NODES; i += 256) {
        unsigned int k = keys[i];
        if (k > P) {
            int pos = atomicAdd(&cnt_gt, 1);
            Mtop[bh*UTOP + pos] = i;
        } else if (k == P) {
            int pos = atomicAdd(&cnt_tie, 1);
            tiebuf[pos] = i;
        }
    }
    __syncthreads();
    const int ngt = cnt_gt;            // == UTOP - r
    const int T = cnt_tie;
    // take the r smallest tie indices (rank by count; ranks distinct -> race-free)
    for (int j = tid; j < T; j += 256) {
        int idx = tiebuf[j];
        int rank = 0;
        for (int t = 0; t < T; ++t) rank += (tiebuf[t] < idx) ? 1 : 0;
        if (rank < r) Mtop[bh*UTOP + ngt + rank] = idx;
    }
}

// ---------------- Kernel 5: scores + softmax + threshold ----------------
__global__ __launch_bounds__(256) void attn_kernel(
    const float* __restrict__ q, const float* __restrict__ k,
    const int* __restrict__ Mtop, float* __restrict__ attn)
{
    __shared__ float qsel[DHEAD];
    __shared__ float sc[NUM_NODES];
    __shared__ float red[8];
    const int blk = blockIdx.x;   // (b*8+h)*40+u
    const int bh = blk / UTOP, u = blk % UTOP;
    const int b = bh >> 3, h = bh & 7;
    const int tid = threadIdx.x;
    const int lsel = Mtop[bh*UTOP + u];
    if (tid < DHEAD) qsel[tid] = q[(size_t)(b*NUM_NODES + lsel)*HID + h*DHEAD + tid];
    __syncthreads();
    const float scale = 0.17677669529663687f; // 1/sqrt(32)
    float lmax = -INFINITY;
    for (int j = tid; j < NUM_NODES; j += 256) {
        const float4* kp = (const float4*)(k + (size_t)(b*NUM_NODES + j)*HID + h*DHEAD);
        const float4* qp = (const float4*)qsel;
        float acc = 0.f;
        #pragma unroll
        for (int d4 = 0; d4 < 8; ++d4) {
            float4 kv = kp[d4], qv = qp[d4];
            acc += qv.x*kv.x + qv.y*kv.y + qv.z*kv.z + qv.w*kv.w;
        }
        acc *= scale;
        sc[j] = acc;
        lmax = fmaxf(lmax, acc);
    }
    #pragma unroll
    for (int m = 32; m >= 1; m >>= 1) lmax = fmaxf(lmax, __shfl_xor(lmax, m));
    if ((tid & 63) == 0) red[tid >> 6] = lmax;
    __syncthreads();
    const float gmax = fmaxf(fmaxf(red[0], red[1]), fmaxf(red[2], red[3]));
    float lsum = 0.f;
    for (int j = tid; j < NUM_NODES; j += 256) {
        float e = expf(sc[j] - gmax);
        sc[j] = e;
        lsum += e;
    }
    #pragma unroll
    for (int m = 32; m >= 1; m >>= 1) lsum += __shfl_xor(lsum, m);
    if ((tid & 63) == 0) red[4 + (tid >> 6)] = lsum;
    __syncthreads();
    const float rinv = 1.0f / (red[4] + red[5] + red[6] + red[7]);
    const float thr = 1.0f / (float)NUM_NODES;
    for (int j4 = tid; j4 < NUM_NODES/4; j4 += 256) {
        float4 v;
        v.x = sc[j4*4+0] * rinv; if (v.x < thr) v.x = 0.f;
        v.y = sc[j4*4+1] * rinv; if (v.y < thr) v.y = 0.f;
        v.z = sc[j4*4+2] * rinv; if (v.z < thr) v.z = 0.f;
        v.w = sc[j4*4+3] * rinv; if (v.w < thr) v.w = 0.f;
        *(float4*)(attn + (size_t)blk*NUM_NODES + j4*4) = v;
    }
}

// ---------------- Kernel 6: combine heads -> output (scans Mtop directly) ----------------
__global__ __launch_bounds__(256) void combine_kernel(
    const float* __restrict__ attn, const int* __restrict__ Mtop,
    float* __restrict__ out)
{
    __shared__ int mtops[NHEAD*UTOP];
    __shared__ int us[NHEAD];
    const int bl = blockIdx.x;  // b*2048+l
    const int b = bl >> 11, l = bl & (NUM_NODES-1);
    const int tid = threadIdx.x;
    if (tid < NHEAD) us[tid] = -1;
    for (int i = tid; i < NHEAD*UTOP; i += 256) mtops[i] = Mtop[b*NHEAD*UTOP + i];
    __syncthreads();
    for (int i = tid; i < NHEAD*UTOP; i += 256) {
        if (mtops[i] == l) us[i / UTOP] = i % UTOP;
    }
    __syncthreads();
    const size_t outbase = (size_t)bl * NUM_NODES;
    for (int j4 = tid; j4 < NUM_NODES/4; j4 += 256) {
        float4 s = make_float4(0.f, 0.f, 0.f, 0.f);
        #pragma unroll
        for (int h = 0; h < NHEAD; ++h) {
            int u = us[h];
            if (u >= 0) {
                float4 a = *(const float4*)(attn + (size_t)((b*NHEAD + h)*UTOP + u)*NUM_NODES + j4*4);
                s.x += a.x; s.y += a.y; s.z += a.z; s.w += a.w;
            }
        }
        s.x *= 0.125f; s.y *= 0.125f; s.z *= 0.125f; s.w *= 0.125f;
        *(float4*)(out + outbase + j4*4) = s;
    }
}

extern "C" void kernel_launch(void* const* d_in, const int* in_sizes, int n_in,
                              void* d_out, int out_size, void* d_ws, size_t ws_size,
                              hipStream_t stream) {
    const float* x      = (const float*)d_in[0];
    const float* w0     = (const float*)d_in[1];
    const float* b0     = (const float*)d_in[2];
    const float* w1     = (const float*)d_in[3];
    const float* b1     = (const float*)d_in[4];
    const float* w2     = (const float*)d_in[5];
    const float* b2     = (const float*)d_in[6];
    const float* g0     = (const float*)d_in[7];
    const float* be0    = (const float*)d_in[8];
    const float* g1     = (const float*)d_in[9];
    const float* be1    = (const float*)d_in[10];
    const float* g2     = (const float*)d_in[11];
    const float* be2    = (const float*)d_in[12];
    const float* g3     = (const float*)d_in[13];
    const float* be3    = (const float*)d_in[14];
    const float* fc_w   = (const float*)d_in[15];
    const float* fc_b   = (const float*)d_in[16];
    const float* q_w    = (const float*)d_in[17];
    const float* q_b    = (const float*)d_in[18];
    const float* k_w    = (const float*)d_in[19];
    const float* k_b    = (const float*)d_in[20];
    const int* idx_g    = (const int*)d_in[21];
    float* out = (float*)d_out;

    float* Hflat   = (float*)d_ws;                       // 4096*608
    float* q_ws    = Hflat + (size_t)ROWS*FCIN;          // 4096*256
    float* k_ws    = q_ws + (size_t)ROWS*HID;            // 4096*256
    float* M_ws    = k_ws + (size_t)ROWS*HID;            // 2*8*2048
    float* attn_ws = M_ws + (size_t)BATCH*NHEAD*NUM_NODES;   // 2*8*40*2048
    int*   Mtop    = (int*)(attn_ws + (size_t)BATCH*NHEAD*UTOP*NUM_NODES); // 640
    float* fc_wT   = (float*)(Mtop + BATCH*NHEAD*UTOP);  // 608*256
    float* q_wT    = fc_wT + (size_t)FCIN*HID;           // 256*256
    float* k_wT    = q_wT + (size_t)HID*HID;             // 256*256

    {
        dim3 tgrid((FCIN + 31)/32, (HID + 31)/32, 3);
        transpose3_kernel<<<tgrid, 256, 0, stream>>>(fc_w, q_w, k_w, fc_wT, q_wT, k_wT);
    }
    conv_chain_kernel<<<ROWS, 128, 0, stream>>>(x, w0, b0, w1, b1, w2, b2,
                                                g0, be0, g1, be1, g2, be2, Hflat);
    fc_qk_kernel<<<ROWS/16, 512, 0, stream>>>(Hflat, fc_wT, fc_b, g3, be3,
                                              q_wT, q_b, k_wT, k_b, q_ws, k_ws);
    qk_sample_kernel<<<BATCH*NUM_NODES, 256, 0, stream>>>(q_ws, k_ws, idx_g, M_ws);
    topk_kernel<<<BATCH*NHEAD, 256, 0, stream>>>(M_ws, Mtop);
    attn_kernel<<<BATCH*NHEAD*UTOP, 256, 0, stream>>>(q_ws, k_ws, Mtop, attn_ws);
    combine_kernel<<<BATCH*NUM_NODES, 256, 0, stream>>>(attn_ws, Mtop, out);
}